// Round 5
// baseline (2354.717 us; speedup 1.0000x reference)
//
#include <hip/hip_runtime.h>
#include <hip/hip_bf16.h>
#include <stdint.h>

#define DEV static __device__ __forceinline__

constexpr int N_ = 50000;
constexpr int E_ = 1600000;
constexpr int G_ = 256;

typedef __attribute__((ext_vector_type(8))) short short8;
typedef __attribute__((ext_vector_type(4))) float float4v;

DEV uint16_t f2bf(float f){
  uint32_t u = __float_as_uint(f);
  uint32_t r = (u + 0x7fffu + ((u >> 16) & 1u)) >> 16;
  return (uint16_t)r;
}
DEV float bf2f(uint16_t v){ return __uint_as_float((uint32_t)v << 16); }
DEV void unpack2(uint32_t p, float& a, float& b){
  a = __uint_as_float(p << 16);
  b = __uint_as_float(p & 0xffff0000u);
}
DEV uint32_t pack2(float a, float b){
  return (uint32_t)f2bf(a) | ((uint32_t)f2bf(b) << 16);
}

// ---------------- x column stats (48 cols over N rows) ----------------
__global__ __launch_bounds__(256) void k_xstats(const float* __restrict__ x, float* __restrict__ xstats){
  __shared__ float lst[96];
  int t = threadIdx.x;
  if (t < 96) lst[t] = 0.f;
  __syncthreads();
  int gid = blockIdx.x * 256 + t;
  int c4 = (gid % 12) * 4;
  float s[4] = {0,0,0,0}, q[4] = {0,0,0,0};
  const float4v* x4 = (const float4v*)x;
  for (int i = gid; i < N_ * 12; i += 64512){
    float4v v = x4[i];
    #pragma unroll
    for (int j = 0; j < 4; j++){ s[j] += v[j]; q[j] += v[j]*v[j]; }
  }
  #pragma unroll
  for (int j = 0; j < 4; j++){
    atomicAdd(&lst[c4 + j], s[j]);
    atomicAdd(&lst[48 + c4 + j], q[j]);
  }
  __syncthreads();
  if (t < 96) atomicAdd(&xstats[t], lst[t]);
}

__global__ void k_xfin(const float* __restrict__ xstats, const float* __restrict__ g,
                       const float* __restrict__ b, float* __restrict__ sx, float* __restrict__ tx){
  int c = threadIdx.x;
  if (c < 48){
    float m = xstats[c] / (float)N_;
    float v = xstats[48 + c] / (float)N_ - m*m;
    float s = g[c] / sqrtf(v + 1e-5f);
    sx[c] = s; tx[c] = b[c] - m*s;
  }
}

// ---------------- histogram of col ----------------
__global__ __launch_bounds__(256) void k_hist(const int* __restrict__ ei, int* __restrict__ counts){
  int e = blockIdx.x * 256 + threadIdx.x;
  if (e < E_) atomicAdd(&counts[ei[E_ + e]], 1);
}

// ---------------- 1/count ----------------
__global__ __launch_bounds__(256) void k_invc(const int* __restrict__ counts, float* __restrict__ invc){
  int n = blockIdx.x * 256 + threadIdx.x;
  if (n < N_){ int c = counts[n]; invc[n] = (c > 0) ? 1.f/(float)c : 0.f; }
}

// ---------------- exclusive scan of counts (single block) ----------------
__global__ __launch_bounds__(256) void k_scan(const int* __restrict__ counts, int* __restrict__ off, int* __restrict__ cur){
  __shared__ int wsum[4];
  __shared__ int carry_s;
  int t = threadIdx.x, lane = t & 63, w = t >> 6;
  if (t == 0) carry_s = 0;
  __syncthreads();
  for (int base = 0; base < N_; base += 1024){
    int i0 = base + t * 4;
    int v0 = (i0 + 0 < N_) ? counts[i0 + 0] : 0;
    int v1 = (i0 + 1 < N_) ? counts[i0 + 1] : 0;
    int v2 = (i0 + 2 < N_) ? counts[i0 + 2] : 0;
    int v3 = (i0 + 3 < N_) ? counts[i0 + 3] : 0;
    int tsum = v0 + v1 + v2 + v3;
    int xs = tsum;
    for (int d = 1; d < 64; d <<= 1){ int y = __shfl_up(xs, d); if (lane >= d) xs += y; }
    if (lane == 63) wsum[w] = xs;
    __syncthreads();
    int woff = 0;
    for (int k = 0; k < w; k++) woff += wsum[k];
    int excl = xs - tsum + woff + carry_s;
    int e0 = excl, e1 = e0 + v0, e2 = e1 + v1, e3 = e2 + v2;
    if (i0 + 0 < N_){ off[i0+0] = e0; cur[i0+0] = e0; }
    if (i0 + 1 < N_){ off[i0+1] = e1; cur[i0+1] = e1; }
    if (i0 + 2 < N_){ off[i0+2] = e2; cur[i0+2] = e2; }
    if (i0 + 3 < N_){ off[i0+3] = e3; cur[i0+3] = e3; }
    __syncthreads();
    if (t == 0) carry_s += wsum[0] + wsum[1] + wsum[2] + wsum[3];
    __syncthreads();
  }
  if (t == 0) off[N_] = carry_s;
}

// ---------------- counting-sort placement (packed int2) ----------------
__global__ __launch_bounds__(256) void k_place(const int* __restrict__ ei, int* __restrict__ cur,
                                               int2* __restrict__ rcs){
  int e = blockIdx.x * 256 + threadIdx.x;
  if (e < E_){
    int c = ei[E_ + e];
    int p = atomicAdd(&cur[c], 1);
    rcs[p] = make_int2(ei[e], c);
  }
}

// ---------------- weight precomputation ----------------
__global__ __launch_bounds__(256) void k_wprep(
    const float* __restrict__ eW2, const float* __restrict__ n1W1,
    const float* __restrict__ n1W2, const float* __restrict__ n2W1,
    const float* __restrict__ n2W2, const float* __restrict__ glW1,
    const float* __restrict__ n1b2, const float* __restrict__ n2b2,
    uint16_t* __restrict__ Mt, float* __restrict__ Wcomb,
    float* __restrict__ M3, float* __restrict__ c1, float* __restrict__ c3){
  int flat = blockIdx.x * 256 + threadIdx.x;
  if (flat < 16384){
    int n = flat & 127, k = flat >> 7;
    float a = 0.f;
    for (int j = 0; j < 128; j++) a += eW2[k*128 + j] * n1W1[(48 + j)*128 + n];
    Mt[n*128 + k] = f2bf(a);
  } else if (flat < 32768){
    int b = flat - 16384;
    int n = b & 127, j = b >> 7;
    float a = 0.f;
    for (int m = 0; m < 128; m++) a += n1W2[j*128 + m] * n2W1[(48 + m)*128 + n];
    Wcomb[(48 + j)*128 + n] = a;
  } else if (flat < 38912){
    int b = flat - 32768;
    int n = b & 127, k = b >> 7;
    Wcomb[k*128 + n] = n2W1[k*128 + n];
  } else if (flat < 55296){
    int b = flat - 38912;
    int n = b & 127, j = b >> 7;
    float a = 0.f;
    for (int m = 0; m < 128; m++) a += n2W2[j*128 + m] * glW1[m*128 + n];
    M3[j*128 + n] = a;
  } else if (flat < 55552){
    int e = flat - 55296;
    if (e < 128){
      float a = 0.f;
      for (int m = 0; m < 128; m++) a += n1b2[m] * n2W1[(48 + m)*128 + e];
      c1[e] = a;
    } else {
      int n = e - 128;
      float a = 0.f;
      for (int m = 0; m < 128; m++) a += n2b2[m] * glW1[m*128 + n];
      c3[n] = a;
    }
  }
}

// ---------------- node GEMM: A,B,C (bf16), coalesced dword stores ----------------
__global__ __launch_bounds__(256) void k_nodegemm(
    const float* __restrict__ x, const float* __restrict__ sx, const float* __restrict__ tx,
    const float* __restrict__ eW1, const float* __restrict__ n1W1,
    uint16_t* __restrict__ AC, uint16_t* __restrict__ Bn){
  __shared__ float xT[48][36];
  __shared__ float W[48][128];
  int t = threadIdx.x;
  int n0 = blockIdx.x * 32;
  for (int idx = t; idx < 384; idx += 256){
    int r = idx / 12, q = idx % 12;
    int n = n0 + r;
    float4v v = {0.f,0.f,0.f,0.f};
    if (n < N_) v = *(const float4v*)&x[(size_t)n*48 + q*4];
    #pragma unroll
    for (int i = 0; i < 4; i++){
      int k = q*4 + i;
      xT[k][r] = v[i] * sx[k] + tx[k];
    }
  }
  int cg = t & 31, ng = t >> 5;
  const float* Wsrc0 = eW1;
  const float* Wsrc1 = eW1 + 48*128;
  const float* Wsrc2 = n1W1;
  for (int seg = 0; seg < 3; seg++){
    const float* Wsrc = (seg == 0) ? Wsrc0 : (seg == 1) ? Wsrc1 : Wsrc2;
    __syncthreads();
    {
      const float4v* src4 = (const float4v*)Wsrc;
      float4v* W4 = (float4v*)W;
      for (int idx = t; idx < 1536; idx += 256) W4[idx] = src4[idx];
    }
    __syncthreads();
    float acc[4][4] = {{0.f}};
    #pragma unroll 4
    for (int k = 0; k < 48; k++){
      float4v xv = *(const float4v*)&xT[k][ng*4];
      float4v wv = *(const float4v*)&W[k][cg*4];
      #pragma unroll
      for (int i = 0; i < 4; i++)
        #pragma unroll
        for (int j = 0; j < 4; j++)
          acc[i][j] += xv[i]*wv[j];
    }
    #pragma unroll
    for (int i = 0; i < 4; i++){
      int n = n0 + ng*4 + i;
      if (n >= N_) continue;
      uint2 pv;
      pv.x = pack2(acc[i][0], acc[i][1]);
      pv.y = pack2(acc[i][2], acc[i][3]);
      if (seg == 0)      *(uint2*)&AC[(size_t)n*256 + cg*4] = pv;
      else if (seg == 1) *(uint2*)&Bn[(size_t)n*128 + cg*4] = pv;
      else               *(uint2*)&AC[(size_t)n*256 + 128 + cg*4] = pv;
    }
  }
}

// ---------------- edge BN stats pass (h1e = A[row]+B[col]) ----------------
__global__ __launch_bounds__(256) void k_estats(const int2* __restrict__ rcs,
    const uint16_t* __restrict__ AC, const uint16_t* __restrict__ Bn, float* __restrict__ estR){
  __shared__ float red[4][64][4];
  __shared__ float lst[256];
  int t = threadIdx.x, lane = t & 63, w = t >> 6;
  int wid = blockIdx.x * 4 + w, nw = gridDim.x * 4;
  float s0=0,q0=0,s1=0,q1=0;
  const uint32_t* ACu = (const uint32_t*)AC;
  const uint32_t* Bu  = (const uint32_t*)Bn;
  for (int e = wid; e < E_; e += nw){
    int2 rc = rcs[e];
    uint32_t pa = ACu[(size_t)rc.x*128 + lane];
    uint32_t pb = Bu[(size_t)rc.y*64 + lane];
    float a0,a1,b0,b1; unpack2(pa,a0,a1); unpack2(pb,b0,b1);
    float h0 = a0 + b0, h1 = a1 + b1;
    s0 += h0; q0 += h0*h0; s1 += h1; q1 += h1*h1;
  }
  red[w][lane][0]=s0; red[w][lane][1]=q0; red[w][lane][2]=s1; red[w][lane][3]=q1;
  __syncthreads();
  if (t < 64){
    float S0=0,Q0=0,S1=0,Q1=0;
    for (int ww = 0; ww < 4; ww++){ S0+=red[ww][t][0]; Q0+=red[ww][t][1]; S1+=red[ww][t][2]; Q1+=red[ww][t][3]; }
    lst[2*t] = S0; lst[2*t+1] = S1; lst[128+2*t] = Q0; lst[128+2*t+1] = Q1;
  }
  __syncthreads();
  atomicAdd(&estR[(blockIdx.x & 63)*256 + t], lst[t]);
}

// ---------------- generic BN finalize ----------------
__global__ void k_bnfin(const float* __restrict__ statsR, int reps, const float* __restrict__ g,
                        const float* __restrict__ be, float* __restrict__ s_out, float* __restrict__ t_out,
                        float inv_n){
  int c = threadIdx.x;
  if (c >= 128) return;
  float sm = 0.f, sq = 0.f;
  for (int r = 0; r < reps; r++){ sm += statsR[r*256 + c]; sq += statsR[r*256 + 128 + c]; }
  float m = sm * inv_n;
  float v = sq * inv_n - m*m;
  float s = g[c] / sqrtf(v + 1e-5f);
  s_out[c] = s;
  t_out[c] = be[c] - m*s;
}

// ---------------- edge MFMA pass 0: h1n = relu_e@M + C[row]; n1 stats; optional h1n store ----------------
// P4 uses the R2/R3-proven batched LDS round-trip (NOT cross-lane chains — R4 regression).
__global__ __launch_bounds__(256) void k_epass0(
    const int2* __restrict__ rcs,
    const uint16_t* __restrict__ AC, const uint16_t* __restrict__ Bn,
    const uint16_t* __restrict__ Mt, const float* __restrict__ se, const float* __restrict__ te,
    float* __restrict__ n1R, uint32_t* __restrict__ h1n, int store){
  __shared__ __align__(16) uint16_t bufA[64*132];   // relu tile -> C tile
  __shared__ __align__(16) uint16_t bufB[128*132];  // Mt -> h tile (rows 0..63)
  __shared__ float sete[256];                       // se | te
  __shared__ float lst[256];
  __shared__ int srow[64], scol[64];
  const int t = threadIdx.x;
  const long i0 = (long)blockIdx.x * 64;
  const int lane = t & 63, w = t >> 6;
  const int m = lane & 15, quad = lane >> 4;

  if (t < 128){ sete[t] = se[t]; sete[128 + t] = te[t]; }
  lst[t] = 0.f;
  if (t < 64){ int2 rc = rcs[i0 + t]; srow[t] = rc.x; scol[t] = rc.y; }
  __syncthreads();

  // P0: stage relu_e into bufA
  {
    int e = t >> 2, q = t & 3;
    int r = srow[e], c = scol[e];
    const uint4* Ap = (const uint4*)((const uint32_t*)AC + (size_t)r*128 + q*16);
    const uint4* Bp = (const uint4*)((const uint32_t*)Bn + (size_t)c*64  + q*16);
    uint4* dst = (uint4*)((uint32_t*)bufA + e*66 + q*16);
    int cb = q*32;
    #pragma unroll
    for (int u = 0; u < 4; u++){
      uint4 va = Ap[u], vb = Bp[u];
      float4v sA = *(const float4v*)&sete[cb + u*8];
      float4v sB = *(const float4v*)&sete[cb + u*8 + 4];
      float4v tA = *(const float4v*)&sete[128 + cb + u*8];
      float4v tB = *(const float4v*)&sete[128 + cb + u*8 + 4];
      float a0,a1,b0,b1; uint4 o;
      unpack2(va.x,a0,a1); unpack2(vb.x,b0,b1);
      o.x = pack2(fmaxf(0.f,(a0+b0)*sA[0]+tA[0]), fmaxf(0.f,(a1+b1)*sA[1]+tA[1]));
      unpack2(va.y,a0,a1); unpack2(vb.y,b0,b1);
      o.y = pack2(fmaxf(0.f,(a0+b0)*sA[2]+tA[2]), fmaxf(0.f,(a1+b1)*sA[3]+tA[3]));
      unpack2(va.z,a0,a1); unpack2(vb.z,b0,b1);
      o.z = pack2(fmaxf(0.f,(a0+b0)*sB[0]+tB[0]), fmaxf(0.f,(a1+b1)*sB[1]+tB[1]));
      unpack2(va.w,a0,a1); unpack2(vb.w,b0,b1);
      o.w = pack2(fmaxf(0.f,(a0+b0)*sB[2]+tB[2]), fmaxf(0.f,(a1+b1)*sB[3]+tB[3]));
      dst[u] = o;
    }
  }
  // P1: stage Mt into bufB
  {
    int n = t >> 1, h = t & 1;
    const uint4* src = (const uint4*)((const uint32_t*)Mt + n*64 + h*32);
    uint4* dst = (uint4*)((uint32_t*)bufB + n*66 + h*32);
    #pragma unroll
    for (int u = 0; u < 8; u++) dst[u] = src[u];
  }
  __syncthreads();

  // P2: MFMA — 16 edges/wave x 128 cols, K=128
  float4v acc[8];
  #pragma unroll
  for (int nt = 0; nt < 8; nt++){ acc[nt][0]=0.f; acc[nt][1]=0.f; acc[nt][2]=0.f; acc[nt][3]=0.f; }
  {
    const uint16_t* aptr = bufA + (w*16 + m)*132 + quad*8;
    const uint16_t* bbase = bufB + m*132 + quad*8;
    #pragma unroll
    for (int ks = 0; ks < 4; ks++){
      short8 af = *(const short8*)(aptr + ks*32);
      #pragma unroll
      for (int nt = 0; nt < 8; nt++){
        short8 bf = *(const short8*)(bbase + nt*16*132 + ks*32);
        acc[nt] = __builtin_amdgcn_mfma_f32_16x16x32_bf16(af, bf, acc[nt], 0, 0, 0);
      }
    }
  }
  __syncthreads();

  // P3: stage C tile into bufA; write acc as bf16 into bufB rows 0..63
  {
    int e = t >> 2, q = t & 3;
    int r = srow[e];
    const uint4* src = (const uint4*)((const uint32_t*)AC + (size_t)r*128 + 64 + q*16);
    uint4* dst = (uint4*)((uint32_t*)bufA + e*66 + q*16);
    #pragma unroll
    for (int u = 0; u < 4; u++) dst[u] = src[u];
  }
  #pragma unroll
  for (int nt = 0; nt < 8; nt++)
    #pragma unroll
    for (int reg = 0; reg < 4; reg++)
      bufB[(w*16 + quad*4 + reg)*132 + nt*16 + m] = f2bf(acc[nt][reg]);
  __syncthreads();

  // P4: h = acc + C, optional coalesced store, batched stats
  {
    int cp = t & 63, eg = t >> 6;
    float ss0=0,qq0=0,ss1=0,qq1=0;
    #pragma unroll
    for (int it = 0; it < 16; it++){
      int e = it*4 + eg;
      uint32_t ph = ((uint32_t*)bufB)[e*66 + cp];
      uint32_t pc = ((uint32_t*)bufA)[e*66 + cp];
      float h0,h1,c0,c1v;
      unpack2(ph,h0,h1); unpack2(pc,c0,c1v);
      float v0 = h0 + c0, v1 = h1 + c1v;
      if (store) h1n[(size_t)(i0 + e)*64 + cp] = pack2(v0, v1);
      ss0 += v0; qq0 += v0*v0; ss1 += v1; qq1 += v1*v1;
    }
    atomicAdd(&lst[2*cp], ss0);
    atomicAdd(&lst[2*cp+1], ss1);
    atomicAdd(&lst[128+2*cp], qq0);
    atomicAdd(&lst[128+2*cp+1], qq1);
  }
  __syncthreads();
  atomicAdd(&n1R[(blockIdx.x & 63)*256 + t], lst[t]);
}

// ---------------- streaming segmented aggregate from stored h1n (store path) ----------------
// aggf[n] = sum over incoming edges of relu(bn1(h1n)); n2 multiplies by invc.
__global__ __launch_bounds__(256) void k_agg(const uint32_t* __restrict__ H, const int* __restrict__ off,
    const float* __restrict__ sn1, const float* __restrict__ tn1, float* __restrict__ aggf){
  int lane = threadIdx.x & 63, w = threadIdx.x >> 6;
  int n = blockIdx.x * 4 + w;
  int b = off[n], e = off[n+1];
  float s0 = sn1[2*lane], s1 = sn1[2*lane+1];
  float t0 = tn1[2*lane], t1 = tn1[2*lane+1];
  float a0 = 0.f, a1 = 0.f;
  for (int i = b; i < e; i++){
    uint32_t p = H[(size_t)i*64 + lane];
    float h0,h1; unpack2(p,h0,h1);
    a0 += fmaxf(0.f, h0*s0 + t0);
    a1 += fmaxf(0.f, h1*s1 + t1);
  }
  float2 o; o.x = a0; o.y = a1;
  *(float2*)&aggf[(size_t)n*128 + 2*lane] = o;
}

// ---------------- edge MFMA pass 1 (fallback path): recompute, BN(n1)+relu, segment-aggregate ----------------
__global__ __launch_bounds__(256) void k_epass1(
    const int2* __restrict__ rcs,
    const uint16_t* __restrict__ AC, const uint16_t* __restrict__ Bn,
    const uint16_t* __restrict__ Mt, const float* __restrict__ se, const float* __restrict__ te,
    const float* __restrict__ sn1, const float* __restrict__ tn1,
    float* __restrict__ aggf){
  __shared__ __align__(16) uint16_t bufA[64*132];
  __shared__ __align__(16) uint16_t bufB[128*132];
  __shared__ float sete[256];
  __shared__ int srow[64], scol[64];
  __shared__ int snseg;
  const int t = threadIdx.x;
  const long i0 = (long)blockIdx.x * 64;
  const int lane = t & 63, w = t >> 6;
  const int m = lane & 15, quad = lane >> 4;

  uint32_t* bufBu = (uint32_t*)bufB;
  float* segacc  = (float*)(bufBu + 4224);
  float* sn1c    = (float*)(bufBu + 7296);
  float* tn1c    = (float*)(bufBu + 7424);
  int*   ssid_s  = (int*)(bufBu + 7552);
  int*   scseg_s = (int*)(bufBu + 7616);

  if (t < 128){ sete[t] = se[t]; sete[128 + t] = te[t]; }
  if (t < 64){ int2 rc = rcs[i0 + t]; srow[t] = rc.x; scol[t] = rc.y; }
  __syncthreads();

  {
    int e = t >> 2, q = t & 3;
    int r = srow[e], c = scol[e];
    const uint4* Ap = (const uint4*)((const uint32_t*)AC + (size_t)r*128 + q*16);
    const uint4* Bp = (const uint4*)((const uint32_t*)Bn + (size_t)c*64  + q*16);
    uint4* dst = (uint4*)((uint32_t*)bufA + e*66 + q*16);
    int cb = q*32;
    #pragma unroll
    for (int u = 0; u < 4; u++){
      uint4 va = Ap[u], vb = Bp[u];
      float4v sA = *(const float4v*)&sete[cb + u*8];
      float4v sB = *(const float4v*)&sete[cb + u*8 + 4];
      float4v tA = *(const float4v*)&sete[128 + cb + u*8];
      float4v tB = *(const float4v*)&sete[128 + cb + u*8 + 4];
      float a0,a1,b0,b1; uint4 o;
      unpack2(va.x,a0,a1); unpack2(vb.x,b0,b1);
      o.x = pack2(fmaxf(0.f,(a0+b0)*sA[0]+tA[0]), fmaxf(0.f,(a1+b1)*sA[1]+tA[1]));
      unpack2(va.y,a0,a1); unpack2(vb.y,b0,b1);
      o.y = pack2(fmaxf(0.f,(a0+b0)*sA[2]+tA[2]), fmaxf(0.f,(a1+b1)*sA[3]+tA[3]));
      unpack2(va.z,a0,a1); unpack2(vb.z,b0,b1);
      o.z = pack2(fmaxf(0.f,(a0+b0)*sB[0]+tB[0]), fmaxf(0.f,(a1+b1)*sB[1]+tB[1]));
      unpack2(va.w,a0,a1); unpack2(vb.w,b0,b1);
      o.w = pack2(fmaxf(0.f,(a0+b0)*sB[2]+tB[2]), fmaxf(0.f,(a1+b1)*sB[3]+tB[3]));
      dst[u] = o;
    }
  }
  {
    int n = t >> 1, h = t & 1;
    const uint4* src = (const uint4*)((const uint32_t*)Mt + n*64 + h*32);
    uint4* dst = (uint4*)((uint32_t*)bufB + n*66 + h*32);
    #pragma unroll
    for (int u = 0; u < 8; u++) dst[u] = src[u];
  }
  __syncthreads();

  float4v acc[8];
  #pragma unroll
  for (int nt = 0; nt < 8; nt++){ acc[nt][0]=0.f; acc[nt][1]=0.f; acc[nt][2]=0.f; acc[nt][3]=0.f; }
  {
    const uint16_t* aptr = bufA + (w*16 + m)*132 + quad*8;
    const uint16_t* bbase = bufB + m*132 + quad*8;
    #pragma unroll
    for (int ks = 0; ks < 4; ks++){
      short8 af = *(const short8*)(aptr + ks*32);
      #pragma unroll
      for (int nt = 0; nt < 8; nt++){
        short8 bf = *(const short8*)(bbase + nt*16*132 + ks*32);
        acc[nt] = __builtin_amdgcn_mfma_f32_16x16x32_bf16(af, bf, acc[nt], 0, 0, 0);
      }
    }
  }
  __syncthreads();

  {
    int e = t >> 2, q = t & 3;
    int r = srow[e];
    const uint4* src = (const uint4*)((const uint32_t*)AC + (size_t)r*128 + 64 + q*16);
    uint4* dst = (uint4*)((uint32_t*)bufA + e*66 + q*16);
    #pragma unroll
    for (int u = 0; u < 4; u++) dst[u] = src[u];
  }
  #pragma unroll
  for (int nt = 0; nt < 8; nt++)
    #pragma unroll
    for (int reg = 0; reg < 4; reg++)
      bufB[(w*16 + quad*4 + reg)*132 + nt*16 + m] = f2bf(acc[nt][reg]);
  if (t < 64){
    bool bnd = (t > 0) && (scol[t] != scol[t-1]);
    unsigned long long mask = __ballot(bnd);
    int sid = __popcll(mask << (63 - t));
    ssid_s[t] = sid;
    if (bnd || t == 0) scseg_s[sid] = scol[t];
    if (t == 63) snseg = sid + 1;
  } else if (t < 192){
    int c = t - 64;
    sn1c[c] = sn1[c]; tn1c[c] = tn1[c];
  }
  for (int i = t; i < 24*128; i += 256) segacc[i] = 0.f;
  __syncthreads();

  {
    int cp = t & 63, eg = t >> 6;
    float s0 = sn1c[2*cp], s1 = sn1c[2*cp+1];
    float b0 = tn1c[2*cp], b1 = tn1c[2*cp+1];
    int nseg = snseg;
    bool lp = (nseg <= 24);
    int cursid = ssid_s[eg*16];
    float r0 = 0.f, r1 = 0.f;
    for (int it = 0; it < 16; it++){
      int e = eg*16 + it;
      uint32_t ph = bufBu[e*66 + cp];
      uint32_t pc = ((uint32_t*)bufA)[e*66 + cp];
      float h0,h1,c0,c1v;
      unpack2(ph,h0,h1); unpack2(pc,c0,c1v);
      float v0 = fmaxf(0.f, (h0+c0)*s0 + b0);
      float v1 = fmaxf(0.f, (h1+c1v)*s1 + b1);
      int sid = ssid_s[e];
      if (sid != cursid){
        if (lp){ atomicAdd(&segacc[cursid*128 + 2*cp], r0); atomicAdd(&segacc[cursid*128 + 2*cp+1], r1); }
        else { int c = scseg_s[cursid];
               atomicAdd(&aggf[(size_t)c*128 + 2*cp], r0); atomicAdd(&aggf[(size_t)c*128 + 2*cp+1], r1); }
        cursid = sid; r0 = 0.f; r1 = 0.f;
      }
      r0 += v0; r1 += v1;
    }
    if (lp){ atomicAdd(&segacc[cursid*128 + 2*cp], r0); atomicAdd(&segacc[cursid*128 + 2*cp+1], r1); }
    else { int c = scseg_s[cursid];
           atomicAdd(&aggf[(size_t)c*128 + 2*cp], r0); atomicAdd(&aggf[(size_t)c*128 + 2*cp+1], r1); }
    __syncthreads();
    if (lp){
      for (int idx = t; idx < nseg*64; idx += 256){
        int s = idx >> 6, cpp = idx & 63;
        float v0 = segacc[s*128 + 2*cpp], v1 = segacc[s*128 + 2*cpp+1];
        int c = scseg_s[s];
        float* dst = &aggf[(size_t)c*128 + 2*cpp];
        if (s == 0 || s == nseg - 1){ atomicAdd(dst, v0); atomicAdd(dst+1, v1); }
        else { dst[0] = v0; dst[1] = v1; }
      }
    }
  }
}

// ---------------- n2 GEMM ----------------
__global__ __launch_bounds__(256) void k_n2(const float* __restrict__ x,
    const float* __restrict__ sx, const float* __restrict__ tx,
    const float* __restrict__ aggf, const float* __restrict__ invc,
    const float* __restrict__ Wc, const float* __restrict__ c1, const int* __restrict__ counts,
    float* __restrict__ hn2, float* __restrict__ n2R){
  __shared__ float xT[44][36];
  __shared__ float wT[44][128];
  __shared__ float lst[256];
  int t = threadIdx.x;
  int n0 = blockIdx.x * 32;
  int cg = t & 31, ng = t >> 5;
  lst[t] = 0.f;
  float acc[4][4] = {{0.f}};
  for (int kc = 0; kc < 176; kc += 44){
    __syncthreads();
    for (int idx = t; idx < 32*44; idx += 256){
      int r = idx / 44, k = idx % 44;
      int n = n0 + r, kk = kc + k;
      float v = 0.f;
      if (n < N_){
        if (kk < 48) v = x[(size_t)n*48 + kk] * sx[kk] + tx[kk];
        else         v = aggf[(size_t)n*128 + (kk - 48)] * invc[n];
      }
      xT[k][r] = v;
    }
    for (int idx = t; idx < 44*128; idx += 256){
      int k = idx >> 7, c = idx & 127;
      wT[k][c] = Wc[(kc + k)*128 + c];
    }
    __syncthreads();
    for (int k = 0; k < 44; k++){
      float4v xv = *(const float4v*)&xT[k][ng*4];
      float4v wv = *(const float4v*)&wT[k][cg*4];
      #pragma unroll
      for (int i = 0; i < 4; i++)
        #pragma unroll
        for (int j = 0; j < 4; j++)
          acc[i][j] += xv[i]*wv[j];
    }
  }
  float csum[4] = {0,0,0,0}, cqs[4] = {0,0,0,0};
  for (int i = 0; i < 4; i++){
    int n = n0 + ng*4 + i;
    if (n >= N_) continue;
    bool ok = counts[n] > 0;
    float4v o;
    #pragma unroll
    for (int j = 0; j < 4; j++){
      float vv = acc[i][j] + (ok ? c1[cg*4 + j] : 0.f);
      o[j] = vv; csum[j] += vv; cqs[j] += vv*vv;
    }
    *(float4v*)&hn2[(size_t)n*128 + cg*4] = o;
  }
  #pragma unroll
  for (int j = 0; j < 4; j++){
    atomicAdd(&lst[cg*4 + j], csum[j]);
    atomicAdd(&lst[128 + cg*4 + j], cqs[j]);
  }
  __syncthreads();
  atomicAdd(&n2R[(blockIdx.x & 63)*256 + t], lst[t]);
}

// ---------------- graph offsets from sorted batch ----------------
__global__ void k_goff(const int* __restrict__ batch, int* __restrict__ goff){
  int g = threadIdx.x;
  int lo = 0, hi = N_;
  while (lo < hi){ int mid = (lo + hi) >> 1; if (batch[mid] < g) lo = mid + 1; else hi = mid; }
  goff[g] = lo;
  if (g == 0) goff[256] = N_;
}

// ---------------- per-graph mean of relu(bn(h_n2)) ----------------
__global__ __launch_bounds__(128) void k_gmean(const float* __restrict__ hn2, const int* __restrict__ goff,
    const float* __restrict__ sn2, const float* __restrict__ tn2, float* __restrict__ gmean){
  int g = blockIdx.x, c = threadIdx.x;
  int b = goff[g], e = goff[g+1];
  float s = sn2[c], tt = tn2[c], a = 0.f;
  for (int r = b; r < e; r++) a += fmaxf(0.f, hn2[(size_t)r*128 + c]*s + tt);
  gmean[g*128 + c] = (e > b) ? a/(float)(e - b) : 0.f;
}

// ---------------- hg = gmean@M3 + cond*c3, gl stats ----------------
__global__ __launch_bounds__(256) void k_hg(const float* __restrict__ gmean, const float* __restrict__ M3,
    const float* __restrict__ c3, const int* __restrict__ goff,
    float* __restrict__ hg, float* __restrict__ gls){
  int idx = blockIdx.x * 256 + threadIdx.x;
  int g = idx >> 7, c = idx & 127;
  float a = 0.f;
  for (int k = 0; k < 128; k++) a += gmean[g*128 + k] * M3[k*128 + c];
  if (goff[g+1] > goff[g]) a += c3[c];
  hg[idx] = a;
  atomicAdd(&gls[c], a);
  atomicAdd(&gls[128 + c], a*a);
}

// ---------------- final output ----------------
__global__ __launch_bounds__(256) void k_out(const float* __restrict__ hg, const float* __restrict__ sgl,
    const float* __restrict__ tgl, const float* __restrict__ glW2, const float* __restrict__ glb2,
    float* __restrict__ out){
  int idx = blockIdx.x * 256 + threadIdx.x;
  int g = idx >> 1, o = idx & 1;
  float a = 0.f;
  for (int c = 0; c < 128; c++){
    float r = fmaxf(0.f, hg[g*128 + c]*sgl[c] + tgl[c]);
    a += r * glW2[c*2 + o];
  }
  out[idx] = a + glb2[o];
}

extern "C" void kernel_launch(void* const* d_in, const int* in_sizes, int n_in,
                              void* d_out, int out_size, void* d_ws, size_t ws_size,
                              hipStream_t stream){
  const float* x     = (const float*)d_in[0];
  const int*   ei    = (const int*)d_in[1];
  const int*   batch = (const int*)d_in[2];
  const float* bn_g  = (const float*)d_in[3];
  const float* bn_b  = (const float*)d_in[4];
  const float* eW1   = (const float*)d_in[5];
  const float* e_g   = (const float*)d_in[7];
  const float* e_be  = (const float*)d_in[8];
  const float* eW2   = (const float*)d_in[9];
  const float* n1W1  = (const float*)d_in[11];
  const float* n1_g  = (const float*)d_in[13];
  const float* n1_be = (const float*)d_in[14];
  const float* n1W2  = (const float*)d_in[15];
  const float* n1b2  = (const float*)d_in[16];
  const float* n2W1  = (const float*)d_in[17];
  const float* n2_g  = (const float*)d_in[19];
  const float* n2_be = (const float*)d_in[20];
  const float* n2W2  = (const float*)d_in[21];
  const float* n2b2  = (const float*)d_in[22];
  const float* glW1  = (const float*)d_in[23];
  const float* gl_g  = (const float*)d_in[25];
  const float* gl_be = (const float*)d_in[26];
  const float* glW2  = (const float*)d_in[27];
  const float* glb2  = (const float*)d_in[28];
  float* out = (float*)d_out;

  char* w = (char*)d_ws;
  size_t off = 0;
  auto take = [&](size_t bytes) -> char* {
    char* p = w + off;
    off = (off + bytes + 511) & ~(size_t)511;
    return p;
  };

  const size_t ZONE_WORDS = 96 + 3*64*256 + 256 + N_;
  float* zone   = (float*)take(ZONE_WORDS * 4);
  float* xstats = zone;
  float* estR   = zone + 96;
  float* n1R    = zone + 96 + 64*256;
  float* n2R    = zone + 96 + 2*64*256;
  float* gls    = zone + 96 + 3*64*256;
  int*   counts = (int*)(zone + 96 + 3*64*256 + 256);

  float* sx = (float*)take(48*4);   float* tx = (float*)take(48*4);
  float* se = (float*)take(128*4);  float* te = (float*)take(128*4);
  float* sn1 = (float*)take(128*4); float* tn1 = (float*)take(128*4);
  float* sn2 = (float*)take(128*4); float* tn2 = (float*)take(128*4);
  float* sgl = (float*)take(128*4); float* tgl = (float*)take(128*4);
  float* c1 = (float*)take(128*4);  float* c3 = (float*)take(128*4);
  float* invc  = (float*)take((size_t)N_*4);
  float* Wcomb = (float*)take(176*128*4);
  float* M3    = (float*)take(128*128*4);
  float* gmean = (float*)take(G_*128*4);
  float* hg    = (float*)take(G_*128*4);
  int* offs = (int*)take((N_+1)*4);
  int* cur  = (int*)take(N_*4);
  int* goff = (int*)take(257*4);
  uint16_t* Mt = (uint16_t*)take(128*128*2);
  uint16_t* AC = (uint16_t*)take((size_t)N_*256*2);
  uint16_t* Bn = (uint16_t*)take((size_t)N_*128*2);
  float* aggf  = (float*)take((size_t)N_*128*4);
  float* hn2   = (float*)take((size_t)N_*128*4);
  int2* rcs = (int2*)take((size_t)E_*8);

  size_t base_off = off;
  if (base_off > ws_size) return;   // clean fail, no fault

  // optional store path: h1n (410 MB). hn2 is dead until after k_agg, so when
  // the store path is active we alias hn2 into the h1n region's tail? No —
  // h1n must stay whole; instead hn2 keeps its base slot (already counted).
  uint32_t* h1n = (uint32_t*)take((size_t)E_*128*2);
  bool store = (off <= ws_size);

  hipMemsetAsync(zone, 0, ZONE_WORDS*4, stream);
  if (!store) hipMemsetAsync(aggf, 0, (size_t)N_*128*4, stream);

  hipLaunchKernelGGL(k_xstats, dim3(252), dim3(256), 0, stream, x, xstats);
  hipLaunchKernelGGL(k_hist, dim3((E_+255)/256), dim3(256), 0, stream, ei, counts);
  hipLaunchKernelGGL(k_xfin, dim3(1), dim3(64), 0, stream, xstats, bn_g, bn_b, sx, tx);
  hipLaunchKernelGGL(k_scan, dim3(1), dim3(256), 0, stream, counts, offs, cur);
  hipLaunchKernelGGL(k_place, dim3((E_+255)/256), dim3(256), 0, stream, ei, cur, rcs);
  hipLaunchKernelGGL(k_invc, dim3((N_+255)/256), dim3(256), 0, stream, counts, invc);
  hipLaunchKernelGGL(k_wprep, dim3(217), dim3(256), 0, stream,
                     eW2, n1W1, n1W2, n2W1, n2W2, glW1, n1b2, n2b2, Mt, Wcomb, M3, c1, c3);
  hipLaunchKernelGGL(k_nodegemm, dim3((N_+31)/32), dim3(256), 0, stream,
                     x, sx, tx, eW1, n1W1, AC, Bn);
  hipLaunchKernelGGL(k_estats, dim3(1024), dim3(256), 0, stream, rcs, AC, Bn, estR);
  hipLaunchKernelGGL(k_bnfin, dim3(1), dim3(128), 0, stream, estR, 64, e_g, e_be, se, te, 1.f/(float)E_);
  hipLaunchKernelGGL(k_epass0, dim3(E_/64), dim3(256), 0, stream,
                     rcs, AC, Bn, Mt, se, te, n1R, h1n, store ? 1 : 0);
  hipLaunchKernelGGL(k_bnfin, dim3(1), dim3(128), 0, stream, n1R, 64, n1_g, n1_be, sn1, tn1, 1.f/(float)E_);
  if (store){
    hipLaunchKernelGGL(k_agg, dim3(N_/4), dim3(256), 0, stream, h1n, offs, sn1, tn1, aggf);
  } else {
    hipLaunchKernelGGL(k_epass1, dim3(E_/64), dim3(256), 0, stream,
                       rcs, AC, Bn, Mt, se, te, sn1, tn1, aggf);
  }
  hipLaunchKernelGGL(k_n2, dim3((N_+31)/32), dim3(256), 0, stream,
                     x, sx, tx, aggf, invc, Wcomb, c1, counts, hn2, n2R);
  hipLaunchKernelGGL(k_bnfin, dim3(1), dim3(128), 0, stream, n2R, 64, n2_g, n2_be, sn2, tn2, 1.f/(float)N_);
  hipLaunchKernelGGL(k_goff, dim3(1), dim3(256), 0, stream, batch, goff);
  hipLaunchKernelGGL(k_gmean, dim3(256), dim3(128), 0, stream, hn2, goff, sn2, tn2, gmean);
  hipLaunchKernelGGL(k_hg, dim3(128), dim3(256), 0, stream, gmean, M3, c3, goff, hg, gls);
  hipLaunchKernelGGL(k_bnfin, dim3(1), dim3(128), 0, stream, gls, 1, gl_g, gl_be, sgl, tgl, 1.f/(float)G_);
  hipLaunchKernelGGL(k_out, dim3(2), dim3(256), 0, stream, hg, sgl, tgl, glW2, glb2, out);
}

// Round 6
// 1851.047 us; speedup vs baseline: 1.2721x; 1.2721x over previous
//
#include <hip/hip_runtime.h>
#include <hip/hip_bf16.h>
#include <stdint.h>

#define DEV static __device__ __forceinline__

constexpr int N_ = 50000;
constexpr int E_ = 1600000;
constexpr int G_ = 256;

typedef __attribute__((ext_vector_type(8))) short short8;
typedef __attribute__((ext_vector_type(4))) float float4v;

DEV uint16_t f2bf(float f){
  uint32_t u = __float_as_uint(f);
  uint32_t r = (u + 0x7fffu + ((u >> 16) & 1u)) >> 16;
  return (uint16_t)r;
}
DEV float bf2f(uint16_t v){ return __uint_as_float((uint32_t)v << 16); }
DEV void unpack2(uint32_t p, float& a, float& b){
  a = __uint_as_float(p << 16);
  b = __uint_as_float(p & 0xffff0000u);
}
DEV uint32_t pack2(float a, float b){
  return (uint32_t)f2bf(a) | ((uint32_t)f2bf(b) << 16);
}

// ---------------- x column stats ----------------
__global__ __launch_bounds__(256) void k_xstats(const float* __restrict__ x, float* __restrict__ xstats){
  __shared__ float lst[96];
  int t = threadIdx.x;
  if (t < 96) lst[t] = 0.f;
  __syncthreads();
  int gid = blockIdx.x * 256 + t;
  int c4 = (gid % 12) * 4;
  float s[4] = {0,0,0,0}, q[4] = {0,0,0,0};
  const float4v* x4 = (const float4v*)x;
  for (int i = gid; i < N_ * 12; i += 64512){
    float4v v = x4[i];
    #pragma unroll
    for (int j = 0; j < 4; j++){ s[j] += v[j]; q[j] += v[j]*v[j]; }
  }
  #pragma unroll
  for (int j = 0; j < 4; j++){
    atomicAdd(&lst[c4 + j], s[j]);
    atomicAdd(&lst[48 + c4 + j], q[j]);
  }
  __syncthreads();
  if (t < 96) atomicAdd(&xstats[t], lst[t]);
}

__global__ void k_xfin(const float* __restrict__ xstats, const float* __restrict__ g,
                       const float* __restrict__ b, float* __restrict__ sx, float* __restrict__ tx){
  int c = threadIdx.x;
  if (c < 48){
    float m = xstats[c] / (float)N_;
    float v = xstats[48 + c] / (float)N_ - m*m;
    float s = g[c] / sqrtf(v + 1e-5f);
    sx[c] = s; tx[c] = b[c] - m*s;
  }
}

// ---------------- histogram of col ----------------
__global__ __launch_bounds__(256) void k_hist(const int* __restrict__ ei, int* __restrict__ counts){
  int e = blockIdx.x * 256 + threadIdx.x;
  if (e < E_) atomicAdd(&counts[ei[E_ + e]], 1);
}

// ---------------- 1/count ----------------
__global__ __launch_bounds__(256) void k_invc(const int* __restrict__ counts, float* __restrict__ invc){
  int n = blockIdx.x * 256 + threadIdx.x;
  if (n < N_){ int c = counts[n]; invc[n] = (c > 0) ? 1.f/(float)c : 0.f; }
}

// ---------------- exclusive scan of counts ----------------
__global__ __launch_bounds__(256) void k_scan(const int* __restrict__ counts, int* __restrict__ off, int* __restrict__ cur){
  __shared__ int wsum[4];
  __shared__ int carry_s;
  int t = threadIdx.x, lane = t & 63, w = t >> 6;
  if (t == 0) carry_s = 0;
  __syncthreads();
  for (int base = 0; base < N_; base += 1024){
    int i0 = base + t * 4;
    int v0 = (i0 + 0 < N_) ? counts[i0 + 0] : 0;
    int v1 = (i0 + 1 < N_) ? counts[i0 + 1] : 0;
    int v2 = (i0 + 2 < N_) ? counts[i0 + 2] : 0;
    int v3 = (i0 + 3 < N_) ? counts[i0 + 3] : 0;
    int tsum = v0 + v1 + v2 + v3;
    int xs = tsum;
    for (int d = 1; d < 64; d <<= 1){ int y = __shfl_up(xs, d); if (lane >= d) xs += y; }
    if (lane == 63) wsum[w] = xs;
    __syncthreads();
    int woff = 0;
    for (int k = 0; k < w; k++) woff += wsum[k];
    int excl = xs - tsum + woff + carry_s;
    int e0 = excl, e1 = e0 + v0, e2 = e1 + v1, e3 = e2 + v2;
    if (i0 + 0 < N_){ off[i0+0] = e0; cur[i0+0] = e0; }
    if (i0 + 1 < N_){ off[i0+1] = e1; cur[i0+1] = e1; }
    if (i0 + 2 < N_){ off[i0+2] = e2; cur[i0+2] = e2; }
    if (i0 + 3 < N_){ off[i0+3] = e3; cur[i0+3] = e3; }
    __syncthreads();
    if (t == 0) carry_s += wsum[0] + wsum[1] + wsum[2] + wsum[3];
    __syncthreads();
  }
  if (t == 0) off[N_] = carry_s;
}

// ---------------- counting-sort placement ----------------
__global__ __launch_bounds__(256) void k_place(const int* __restrict__ ei, int* __restrict__ cur,
                                               int2* __restrict__ rcs){
  int e = blockIdx.x * 256 + threadIdx.x;
  if (e < E_){
    int c = ei[E_ + e];
    int p = atomicAdd(&cur[c], 1);
    rcs[p] = make_int2(ei[e], c);
  }
}

// ---------------- weight precomputation ----------------
__global__ __launch_bounds__(256) void k_wprep(
    const float* __restrict__ eW2, const float* __restrict__ n1W1,
    const float* __restrict__ n1W2, const float* __restrict__ n2W1,
    const float* __restrict__ n2W2, const float* __restrict__ glW1,
    const float* __restrict__ n1b2, const float* __restrict__ n2b2,
    uint16_t* __restrict__ Mt, float* __restrict__ Wcomb,
    float* __restrict__ M3, float* __restrict__ c1, float* __restrict__ c3){
  int flat = blockIdx.x * 256 + threadIdx.x;
  if (flat < 16384){
    int n = flat & 127, k = flat >> 7;
    float a = 0.f;
    for (int j = 0; j < 128; j++) a += eW2[k*128 + j] * n1W1[(48 + j)*128 + n];
    Mt[n*128 + k] = f2bf(a);
  } else if (flat < 32768){
    int b = flat - 16384;
    int n = b & 127, j = b >> 7;
    float a = 0.f;
    for (int m = 0; m < 128; m++) a += n1W2[j*128 + m] * n2W1[(48 + m)*128 + n];
    Wcomb[(48 + j)*128 + n] = a;
  } else if (flat < 38912){
    int b = flat - 32768;
    int n = b & 127, k = b >> 7;
    Wcomb[k*128 + n] = n2W1[k*128 + n];
  } else if (flat < 55296){
    int b = flat - 38912;
    int n = b & 127, j = b >> 7;
    float a = 0.f;
    for (int m = 0; m < 128; m++) a += n2W2[j*128 + m] * glW1[m*128 + n];
    M3[j*128 + n] = a;
  } else if (flat < 55552){
    int e = flat - 55296;
    if (e < 128){
      float a = 0.f;
      for (int m = 0; m < 128; m++) a += n1b2[m] * n2W1[(48 + m)*128 + e];
      c1[e] = a;
    } else {
      int n = e - 128;
      float a = 0.f;
      for (int m = 0; m < 128; m++) a += n2b2[m] * glW1[m*128 + n];
      c3[n] = a;
    }
  }
}

// ---------------- node GEMM: A,B,C (bf16) ----------------
__global__ __launch_bounds__(256) void k_nodegemm(
    const float* __restrict__ x, const float* __restrict__ sx, const float* __restrict__ tx,
    const float* __restrict__ eW1, const float* __restrict__ n1W1,
    uint16_t* __restrict__ AC, uint16_t* __restrict__ Bn){
  __shared__ float xT[48][36];
  __shared__ float W[48][128];
  int t = threadIdx.x;
  int n0 = blockIdx.x * 32;
  for (int idx = t; idx < 384; idx += 256){
    int r = idx / 12, q = idx % 12;
    int n = n0 + r;
    float4v v = {0.f,0.f,0.f,0.f};
    if (n < N_) v = *(const float4v*)&x[(size_t)n*48 + q*4];
    #pragma unroll
    for (int i = 0; i < 4; i++){
      int k = q*4 + i;
      xT[k][r] = v[i] * sx[k] + tx[k];
    }
  }
  int cg = t & 31, ng = t >> 5;
  const float* Wsrc0 = eW1;
  const float* Wsrc1 = eW1 + 48*128;
  const float* Wsrc2 = n1W1;
  for (int seg = 0; seg < 3; seg++){
    const float* Wsrc = (seg == 0) ? Wsrc0 : (seg == 1) ? Wsrc1 : Wsrc2;
    __syncthreads();
    {
      const float4v* src4 = (const float4v*)Wsrc;
      float4v* W4 = (float4v*)W;
      for (int idx = t; idx < 1536; idx += 256) W4[idx] = src4[idx];
    }
    __syncthreads();
    float acc[4][4] = {{0.f}};
    #pragma unroll 4
    for (int k = 0; k < 48; k++){
      float4v xv = *(const float4v*)&xT[k][ng*4];
      float4v wv = *(const float4v*)&W[k][cg*4];
      #pragma unroll
      for (int i = 0; i < 4; i++)
        #pragma unroll
        for (int j = 0; j < 4; j++)
          acc[i][j] += xv[i]*wv[j];
    }
    #pragma unroll
    for (int i = 0; i < 4; i++){
      int n = n0 + ng*4 + i;
      if (n >= N_) continue;
      uint2 pv;
      pv.x = pack2(acc[i][0], acc[i][1]);
      pv.y = pack2(acc[i][2], acc[i][3]);
      if (seg == 0)      *(uint2*)&AC[(size_t)n*256 + cg*4] = pv;
      else if (seg == 1) *(uint2*)&Bn[(size_t)n*128 + cg*4] = pv;
      else               *(uint2*)&AC[(size_t)n*256 + 128 + cg*4] = pv;
    }
  }
}

// ---------------- edge BN stats pass (h1e = A[row]+B[col]) ----------------
__global__ __launch_bounds__(256) void k_estats(const int2* __restrict__ rcs,
    const uint16_t* __restrict__ AC, const uint16_t* __restrict__ Bn, float* __restrict__ estR){
  __shared__ float red[4][64][4];
  __shared__ float lst[256];
  int t = threadIdx.x, lane = t & 63, w = t >> 6;
  int wid = blockIdx.x * 4 + w, nw = gridDim.x * 4;
  float s0=0,q0=0,s1=0,q1=0;
  const uint32_t* ACu = (const uint32_t*)AC;
  const uint32_t* Bu  = (const uint32_t*)Bn;
  for (int e = wid; e < E_; e += nw){
    int2 rc = rcs[e];
    uint32_t pa = ACu[(size_t)rc.x*128 + lane];
    uint32_t pb = Bu[(size_t)rc.y*64 + lane];
    float a0,a1,b0,b1; unpack2(pa,a0,a1); unpack2(pb,b0,b1);
    float h0 = a0 + b0, h1 = a1 + b1;
    s0 += h0; q0 += h0*h0; s1 += h1; q1 += h1*h1;
  }
  red[w][lane][0]=s0; red[w][lane][1]=q0; red[w][lane][2]=s1; red[w][lane][3]=q1;
  __syncthreads();
  if (t < 64){
    float S0=0,Q0=0,S1=0,Q1=0;
    for (int ww = 0; ww < 4; ww++){ S0+=red[ww][t][0]; Q0+=red[ww][t][1]; S1+=red[ww][t][2]; Q1+=red[ww][t][3]; }
    lst[2*t] = S0; lst[2*t+1] = S1; lst[128+2*t] = Q0; lst[128+2*t+1] = Q1;
  }
  __syncthreads();
  atomicAdd(&estR[(blockIdx.x & 63)*256 + t], lst[t]);
}

// ---------------- generic BN finalize ----------------
__global__ void k_bnfin(const float* __restrict__ statsR, int reps, const float* __restrict__ g,
                        const float* __restrict__ be, float* __restrict__ s_out, float* __restrict__ t_out,
                        float inv_n){
  int c = threadIdx.x;
  if (c >= 128) return;
  float sm = 0.f, sq = 0.f;
  for (int r = 0; r < reps; r++){ sm += statsR[r*256 + c]; sq += statsR[r*256 + 128 + c]; }
  float m = sm * inv_n;
  float v = sq * inv_n - m*m;
  float s = g[c] / sqrtf(v + 1e-5f);
  s_out[c] = s;
  t_out[c] = be[c] - m*s;
}

// ---------------- edge MFMA pass 0: n1 BN stats ----------------
// Stride 136 (16B-aligned rows — the R4/R5 regression was stride-132 misalignment).
// B-fragments read directly from global Mt (L1-resident) — no LDS Mt buffer.
__global__ __launch_bounds__(256) void k_epass0(
    const int2* __restrict__ rcs,
    const uint16_t* __restrict__ AC, const uint16_t* __restrict__ Bn,
    const uint16_t* __restrict__ Mt, const float* __restrict__ se, const float* __restrict__ te,
    float* __restrict__ n1R){
  __shared__ __align__(16) uint16_t bufA[64*136];   // relu tile -> C tile
  __shared__ float sete[256];                       // se | te
  __shared__ float lst[256];
  __shared__ int srow[64], scol[64];
  const int t = threadIdx.x;
  const long i0 = (long)blockIdx.x * 64;
  const int lane = t & 63, w = t >> 6;
  const int m = lane & 15, quad = lane >> 4;

  if (t < 128){ sete[t] = se[t]; sete[128 + t] = te[t]; }
  lst[t] = 0.f;
  if (t < 64){ int2 rc = rcs[i0 + t]; srow[t] = rc.x; scol[t] = rc.y; }
  __syncthreads();

  // P0: stage relu_e into bufA
  {
    int e = t >> 2, q = t & 3;
    int r = srow[e], c = scol[e];
    const uint4* Ap = (const uint4*)((const uint32_t*)AC + (size_t)r*128 + q*16);
    const uint4* Bp = (const uint4*)((const uint32_t*)Bn + (size_t)c*64  + q*16);
    uint4* dst = (uint4*)((uint32_t*)bufA + e*68 + q*16);
    int cb = q*32;
    #pragma unroll
    for (int u = 0; u < 4; u++){
      uint4 va = Ap[u], vb = Bp[u];
      float4v sA = *(const float4v*)&sete[cb + u*8];
      float4v sB = *(const float4v*)&sete[cb + u*8 + 4];
      float4v tA = *(const float4v*)&sete[128 + cb + u*8];
      float4v tB = *(const float4v*)&sete[128 + cb + u*8 + 4];
      float a0,a1,b0,b1; uint4 o;
      unpack2(va.x,a0,a1); unpack2(vb.x,b0,b1);
      o.x = pack2(fmaxf(0.f,(a0+b0)*sA[0]+tA[0]), fmaxf(0.f,(a1+b1)*sA[1]+tA[1]));
      unpack2(va.y,a0,a1); unpack2(vb.y,b0,b1);
      o.y = pack2(fmaxf(0.f,(a0+b0)*sA[2]+tA[2]), fmaxf(0.f,(a1+b1)*sA[3]+tA[3]));
      unpack2(va.z,a0,a1); unpack2(vb.z,b0,b1);
      o.z = pack2(fmaxf(0.f,(a0+b0)*sB[0]+tB[0]), fmaxf(0.f,(a1+b1)*sB[1]+tB[1]));
      unpack2(va.w,a0,a1); unpack2(vb.w,b0,b1);
      o.w = pack2(fmaxf(0.f,(a0+b0)*sB[2]+tB[2]), fmaxf(0.f,(a1+b1)*sB[3]+tB[3]));
      dst[u] = o;
    }
  }
  __syncthreads();

  // P2: MFMA — A from LDS, B direct from global Mt (L1-hot)
  float4v acc[8];
  #pragma unroll
  for (int nt = 0; nt < 8; nt++){ acc[nt][0]=0.f; acc[nt][1]=0.f; acc[nt][2]=0.f; acc[nt][3]=0.f; }
  {
    const uint16_t* aptr = bufA + (w*16 + m)*136 + quad*8;
    const uint16_t* mbase = Mt + m*128 + quad*8;
    #pragma unroll
    for (int ks = 0; ks < 4; ks++){
      short8 af = *(const short8*)(aptr + ks*32);
      #pragma unroll
      for (int nt = 0; nt < 8; nt++){
        short8 bf = *(const short8*)(mbase + nt*16*128 + ks*32);
        acc[nt] = __builtin_amdgcn_mfma_f32_16x16x32_bf16(af, bf, acc[nt], 0, 0, 0);
      }
    }
  }
  __syncthreads();

  // P3: stage C tile into bufA
  {
    int e = t >> 2, q = t & 3;
    int r = srow[e];
    const uint4* src = (const uint4*)((const uint32_t*)AC + (size_t)r*128 + 64 + q*16);
    uint4* dst = (uint4*)((uint32_t*)bufA + e*68 + q*16);
    #pragma unroll
    for (int u = 0; u < 4; u++) dst[u] = src[u];
  }
  __syncthreads();

  // P4: per-lane stats from acc + C, cross-quad shuffle reduce
  #pragma unroll
  for (int nt = 0; nt < 8; nt++){
    int col = nt*16 + m;
    float ss = 0.f, qq = 0.f;
    #pragma unroll
    for (int reg = 0; reg < 4; reg++){
      int e = w*16 + quad*4 + reg;
      float cv = bf2f(bufA[e*136 + col]);
      float h = acc[nt][reg] + cv;
      ss += h; qq += h*h;
    }
    ss += __shfl_xor(ss, 16); ss += __shfl_xor(ss, 32);
    qq += __shfl_xor(qq, 16); qq += __shfl_xor(qq, 32);
    if (quad == 0){
      atomicAdd(&lst[col], ss);
      atomicAdd(&lst[128 + col], qq);
    }
  }
  __syncthreads();
  atomicAdd(&n1R[(blockIdx.x & 63)*256 + t], lst[t]);
}

// ---------------- edge MFMA pass 1: recompute, BN(n1)+relu, segment-aggregate ----------------
__global__ __launch_bounds__(256) void k_epass1(
    const int2* __restrict__ rcs,
    const uint16_t* __restrict__ AC, const uint16_t* __restrict__ Bn,
    const uint16_t* __restrict__ Mt, const float* __restrict__ se, const float* __restrict__ te,
    const float* __restrict__ sn1, const float* __restrict__ tn1,
    float* __restrict__ aggf){
  __shared__ __align__(16) uint16_t bufA[64*136];   // relu tile -> C tile
  __shared__ __align__(16) uint16_t bufH[64*136];   // BN+relu'd h tile
  __shared__ float segacc[24*128];
  __shared__ float sete[256];                       // se | te
  __shared__ float snc[256];                        // sn1 | tn1
  __shared__ int srow[64], scol[64], ssid_s[64], scseg_s[64];
  __shared__ int snseg;
  const int t = threadIdx.x;
  const long i0 = (long)blockIdx.x * 64;
  const int lane = t & 63, w = t >> 6;
  const int m = lane & 15, quad = lane >> 4;

  if (t < 128){ sete[t] = se[t]; sete[128 + t] = te[t]; snc[t] = sn1[t]; snc[128 + t] = tn1[t]; }
  if (t < 64){ int2 rc = rcs[i0 + t]; srow[t] = rc.x; scol[t] = rc.y; }
  __syncthreads();

  // segment ids from sorted col + zero segacc + P0 staging
  if (t < 64){
    bool bnd = (t > 0) && (scol[t] != scol[t-1]);
    unsigned long long mask = __ballot(bnd);
    int sid = __popcll(mask << (63 - t));
    ssid_s[t] = sid;
    if (bnd || t == 0) scseg_s[sid] = scol[t];
    if (t == 63) snseg = sid + 1;
  }
  for (int i = t; i < 24*128; i += 256) segacc[i] = 0.f;
  // P0: stage relu_e into bufA
  {
    int e = t >> 2, q = t & 3;
    int r = srow[e], c = scol[e];
    const uint4* Ap = (const uint4*)((const uint32_t*)AC + (size_t)r*128 + q*16);
    const uint4* Bp = (const uint4*)((const uint32_t*)Bn + (size_t)c*64  + q*16);
    uint4* dst = (uint4*)((uint32_t*)bufA + e*68 + q*16);
    int cb = q*32;
    #pragma unroll
    for (int u = 0; u < 4; u++){
      uint4 va = Ap[u], vb = Bp[u];
      float4v sA = *(const float4v*)&sete[cb + u*8];
      float4v sB = *(const float4v*)&sete[cb + u*8 + 4];
      float4v tA = *(const float4v*)&sete[128 + cb + u*8];
      float4v tB = *(const float4v*)&sete[128 + cb + u*8 + 4];
      float a0,a1,b0,b1; uint4 o;
      unpack2(va.x,a0,a1); unpack2(vb.x,b0,b1);
      o.x = pack2(fmaxf(0.f,(a0+b0)*sA[0]+tA[0]), fmaxf(0.f,(a1+b1)*sA[1]+tA[1]));
      unpack2(va.y,a0,a1); unpack2(vb.y,b0,b1);
      o.y = pack2(fmaxf(0.f,(a0+b0)*sA[2]+tA[2]), fmaxf(0.f,(a1+b1)*sA[3]+tA[3]));
      unpack2(va.z,a0,a1); unpack2(vb.z,b0,b1);
      o.z = pack2(fmaxf(0.f,(a0+b0)*sB[0]+tB[0]), fmaxf(0.f,(a1+b1)*sB[1]+tB[1]));
      unpack2(va.w,a0,a1); unpack2(vb.w,b0,b1);
      o.w = pack2(fmaxf(0.f,(a0+b0)*sB[2]+tB[2]), fmaxf(0.f,(a1+b1)*sB[3]+tB[3]));
      dst[u] = o;
    }
  }
  __syncthreads();

  // P2: MFMA — A from LDS, B direct from global Mt
  float4v acc[8];
  #pragma unroll
  for (int nt = 0; nt < 8; nt++){ acc[nt][0]=0.f; acc[nt][1]=0.f; acc[nt][2]=0.f; acc[nt][3]=0.f; }
  {
    const uint16_t* aptr = bufA + (w*16 + m)*136 + quad*8;
    const uint16_t* mbase = Mt + m*128 + quad*8;
    #pragma unroll
    for (int ks = 0; ks < 4; ks++){
      short8 af = *(const short8*)(aptr + ks*32);
      #pragma unroll
      for (int nt = 0; nt < 8; nt++){
        short8 bf = *(const short8*)(mbase + nt*16*128 + ks*32);
        acc[nt] = __builtin_amdgcn_mfma_f32_16x16x32_bf16(af, bf, acc[nt], 0, 0, 0);
      }
    }
  }
  __syncthreads();

  // P3: stage C tile into bufA
  {
    int e = t >> 2, q = t & 3;
    int r = srow[e];
    const uint4* src = (const uint4*)((const uint32_t*)AC + (size_t)r*128 + 64 + q*16);
    uint4* dst = (uint4*)((uint32_t*)bufA + e*68 + q*16);
    #pragma unroll
    for (int u = 0; u < 4; u++) dst[u] = src[u];
  }
  __syncthreads();

  // P3b: v = relu(bn1(acc + C)) -> bufH (bf16)
  #pragma unroll
  for (int nt = 0; nt < 8; nt++){
    int col = nt*16 + m;
    float sc = snc[col], sh = snc[128 + col];
    #pragma unroll
    for (int reg = 0; reg < 4; reg++){
      int e = w*16 + quad*4 + reg;
      float cv = bf2f(bufA[e*136 + col]);
      float v = fmaxf(0.f, (acc[nt][reg] + cv)*sc + sh);
      bufH[e*136 + col] = f2bf(v);
    }
  }
  __syncthreads();

  // P4: batched segment walk over bufH
  {
    int cp = t & 63, eg = t >> 6;
    int nseg = snseg;
    bool lp = (nseg <= 24);
    int cursid = ssid_s[eg*16];
    float r0 = 0.f, r1 = 0.f;
    const uint32_t* Hu = (const uint32_t*)bufH;
    for (int it = 0; it < 16; it++){
      int e = eg*16 + it;
      uint32_t ph = Hu[e*68 + cp];
      float v0, v1; unpack2(ph, v0, v1);
      int sid = ssid_s[e];
      if (sid != cursid){
        if (lp){ atomicAdd(&segacc[cursid*128 + 2*cp], r0); atomicAdd(&segacc[cursid*128 + 2*cp+1], r1); }
        else { int c = scseg_s[cursid];
               atomicAdd(&aggf[(size_t)c*128 + 2*cp], r0); atomicAdd(&aggf[(size_t)c*128 + 2*cp+1], r1); }
        cursid = sid; r0 = 0.f; r1 = 0.f;
      }
      r0 += v0; r1 += v1;
    }
    if (lp){ atomicAdd(&segacc[cursid*128 + 2*cp], r0); atomicAdd(&segacc[cursid*128 + 2*cp+1], r1); }
    else { int c = scseg_s[cursid];
           atomicAdd(&aggf[(size_t)c*128 + 2*cp], r0); atomicAdd(&aggf[(size_t)c*128 + 2*cp+1], r1); }
    __syncthreads();
    if (lp){
      for (int idx = t; idx < nseg*64; idx += 256){
        int s = idx >> 6, cpp = idx & 63;
        float v0 = segacc[s*128 + 2*cpp], v1 = segacc[s*128 + 2*cpp+1];
        int c = scseg_s[s];
        float* dst = &aggf[(size_t)c*128 + 2*cpp];
        if (s == 0 || s == nseg - 1){ atomicAdd(dst, v0); atomicAdd(dst+1, v1); }
        else { dst[0] = v0; dst[1] = v1; }   // middle col wholly owned by this block
      }
    }
  }
}

// ---------------- n2 GEMM ----------------
__global__ __launch_bounds__(256) void k_n2(const float* __restrict__ x,
    const float* __restrict__ sx, const float* __restrict__ tx,
    const float* __restrict__ aggf, const float* __restrict__ invc,
    const float* __restrict__ Wc, const float* __restrict__ c1, const int* __restrict__ counts,
    float* __restrict__ hn2, float* __restrict__ n2R){
  __shared__ float xT[44][36];
  __shared__ float wT[44][128];
  __shared__ float lst[256];
  int t = threadIdx.x;
  int n0 = blockIdx.x * 32;
  int cg = t & 31, ng = t >> 5;
  lst[t] = 0.f;
  float acc[4][4] = {{0.f}};
  for (int kc = 0; kc < 176; kc += 44){
    __syncthreads();
    for (int idx = t; idx < 32*44; idx += 256){
      int r = idx / 44, k = idx % 44;
      int n = n0 + r, kk = kc + k;
      float v = 0.f;
      if (n < N_){
        if (kk < 48) v = x[(size_t)n*48 + kk] * sx[kk] + tx[kk];
        else         v = aggf[(size_t)n*128 + (kk - 48)] * invc[n];
      }
      xT[k][r] = v;
    }
    for (int idx = t; idx < 44*128; idx += 256){
      int k = idx >> 7, c = idx & 127;
      wT[k][c] = Wc[(kc + k)*128 + c];
    }
    __syncthreads();
    for (int k = 0; k < 44; k++){
      float4v xv = *(const float4v*)&xT[k][ng*4];
      float4v wv = *(const float4v*)&wT[k][cg*4];
      #pragma unroll
      for (int i = 0; i < 4; i++)
        #pragma unroll
        for (int j = 0; j < 4; j++)
          acc[i][j] += xv[i]*wv[j];
    }
  }
  float csum[4] = {0,0,0,0}, cqs[4] = {0,0,0,0};
  for (int i = 0; i < 4; i++){
    int n = n0 + ng*4 + i;
    if (n >= N_) continue;
    bool ok = counts[n] > 0;
    float4v o;
    #pragma unroll
    for (int j = 0; j < 4; j++){
      float vv = acc[i][j] + (ok ? c1[cg*4 + j] : 0.f);
      o[j] = vv; csum[j] += vv; cqs[j] += vv*vv;
    }
    *(float4v*)&hn2[(size_t)n*128 + cg*4] = o;
  }
  #pragma unroll
  for (int j = 0; j < 4; j++){
    atomicAdd(&lst[cg*4 + j], csum[j]);
    atomicAdd(&lst[128 + cg*4 + j], cqs[j]);
  }
  __syncthreads();
  atomicAdd(&n2R[(blockIdx.x & 63)*256 + t], lst[t]);
}

// ---------------- graph offsets from sorted batch ----------------
__global__ void k_goff(const int* __restrict__ batch, int* __restrict__ goff){
  int g = threadIdx.x;
  int lo = 0, hi = N_;
  while (lo < hi){ int mid = (lo + hi) >> 1; if (batch[mid] < g) lo = mid + 1; else hi = mid; }
  goff[g] = lo;
  if (g == 0) goff[256] = N_;
}

// ---------------- per-graph mean of relu(bn(h_n2)) ----------------
__global__ __launch_bounds__(128) void k_gmean(const float* __restrict__ hn2, const int* __restrict__ goff,
    const float* __restrict__ sn2, const float* __restrict__ tn2, float* __restrict__ gmean){
  int g = blockIdx.x, c = threadIdx.x;
  int b = goff[g], e = goff[g+1];
  float s = sn2[c], tt = tn2[c], a = 0.f;
  for (int r = b; r < e; r++) a += fmaxf(0.f, hn2[(size_t)r*128 + c]*s + tt);
  gmean[g*128 + c] = (e > b) ? a/(float)(e - b) : 0.f;
}

// ---------------- hg = gmean@M3 + cond*c3, gl stats ----------------
__global__ __launch_bounds__(256) void k_hg(const float* __restrict__ gmean, const float* __restrict__ M3,
    const float* __restrict__ c3, const int* __restrict__ goff,
    float* __restrict__ hg, float* __restrict__ gls){
  int idx = blockIdx.x * 256 + threadIdx.x;
  int g = idx >> 7, c = idx & 127;
  float a = 0.f;
  for (int k = 0; k < 128; k++) a += gmean[g*128 + k] * M3[k*128 + c];
  if (goff[g+1] > goff[g]) a += c3[c];
  hg[idx] = a;
  atomicAdd(&gls[c], a);
  atomicAdd(&gls[128 + c], a*a);
}

// ---------------- final output ----------------
__global__ __launch_bounds__(256) void k_out(const float* __restrict__ hg, const float* __restrict__ sgl,
    const float* __restrict__ tgl, const float* __restrict__ glW2, const float* __restrict__ glb2,
    float* __restrict__ out){
  int idx = blockIdx.x * 256 + threadIdx.x;
  int g = idx >> 1, o = idx & 1;
  float a = 0.f;
  for (int c = 0; c < 128; c++){
    float r = fmaxf(0.f, hg[g*128 + c]*sgl[c] + tgl[c]);
    a += r * glW2[c*2 + o];
  }
  out[idx] = a + glb2[o];
}

extern "C" void kernel_launch(void* const* d_in, const int* in_sizes, int n_in,
                              void* d_out, int out_size, void* d_ws, size_t ws_size,
                              hipStream_t stream){
  const float* x     = (const float*)d_in[0];
  const int*   ei    = (const int*)d_in[1];
  const int*   batch = (const int*)d_in[2];
  const float* bn_g  = (const float*)d_in[3];
  const float* bn_b  = (const float*)d_in[4];
  const float* eW1   = (const float*)d_in[5];
  const float* e_g   = (const float*)d_in[7];
  const float* e_be  = (const float*)d_in[8];
  const float* eW2   = (const float*)d_in[9];
  const float* n1W1  = (const float*)d_in[11];
  const float* n1_g  = (const float*)d_in[13];
  const float* n1_be = (const float*)d_in[14];
  const float* n1W2  = (const float*)d_in[15];
  const float* n1b2  = (const float*)d_in[16];
  const float* n2W1  = (const float*)d_in[17];
  const float* n2_g  = (const float*)d_in[19];
  const float* n2_be = (const float*)d_in[20];
  const float* n2W2  = (const float*)d_in[21];
  const float* n2b2  = (const float*)d_in[22];
  const float* glW1  = (const float*)d_in[23];
  const float* gl_g  = (const float*)d_in[25];
  const float* gl_be = (const float*)d_in[26];
  const float* glW2  = (const float*)d_in[27];
  const float* glb2  = (const float*)d_in[28];
  float* out = (float*)d_out;

  char* w = (char*)d_ws;
  size_t off = 0;
  auto take = [&](size_t bytes) -> char* {
    char* p = w + off;
    off = (off + bytes + 511) & ~(size_t)511;
    return p;
  };

  const size_t ZONE_WORDS = 96 + 3*64*256 + 256 + N_;
  float* zone   = (float*)take(ZONE_WORDS * 4);
  float* xstats = zone;
  float* estR   = zone + 96;
  float* n1R    = zone + 96 + 64*256;
  float* n2R    = zone + 96 + 2*64*256;
  float* gls    = zone + 96 + 3*64*256;
  int*   counts = (int*)(zone + 96 + 3*64*256 + 256);

  float* sx = (float*)take(48*4);   float* tx = (float*)take(48*4);
  float* se = (float*)take(128*4);  float* te = (float*)take(128*4);
  float* sn1 = (float*)take(128*4); float* tn1 = (float*)take(128*4);
  float* sn2 = (float*)take(128*4); float* tn2 = (float*)take(128*4);
  float* sgl = (float*)take(128*4); float* tgl = (float*)take(128*4);
  float* c1 = (float*)take(128*4);  float* c3 = (float*)take(128*4);
  float* invc  = (float*)take((size_t)N_*4);
  float* Wcomb = (float*)take(176*128*4);
  float* M3    = (float*)take(128*128*4);
  float* gmean = (float*)take(G_*128*4);
  float* hg    = (float*)take(G_*128*4);
  int* offs = (int*)take((N_+1)*4);
  int* cur  = (int*)take(N_*4);
  int* goff = (int*)take(257*4);
  uint16_t* Mt = (uint16_t*)take(128*128*2);
  uint16_t* AC = (uint16_t*)take((size_t)N_*256*2);
  uint16_t* Bn = (uint16_t*)take((size_t)N_*128*2);
  float* aggf  = (float*)take((size_t)N_*128*4);
  float* hn2   = (float*)take((size_t)N_*128*4);
  int2* rcs = (int2*)take((size_t)E_*8);

  if (off > ws_size) return;   // clean fail, no fault

  hipMemsetAsync(zone, 0, ZONE_WORDS*4, stream);
  hipMemsetAsync(aggf, 0, (size_t)N_*128*4, stream);

  hipLaunchKernelGGL(k_xstats, dim3(252), dim3(256), 0, stream, x, xstats);
  hipLaunchKernelGGL(k_hist, dim3((E_+255)/256), dim3(256), 0, stream, ei, counts);
  hipLaunchKernelGGL(k_xfin, dim3(1), dim3(64), 0, stream, xstats, bn_g, bn_b, sx, tx);
  hipLaunchKernelGGL(k_scan, dim3(1), dim3(256), 0, stream, counts, offs, cur);
  hipLaunchKernelGGL(k_place, dim3((E_+255)/256), dim3(256), 0, stream, ei, cur, rcs);
  hipLaunchKernelGGL(k_invc, dim3((N_+255)/256), dim3(256), 0, stream, counts, invc);
  hipLaunchKernelGGL(k_wprep, dim3(217), dim3(256), 0, stream,
                     eW2, n1W1, n1W2, n2W1, n2W2, glW1, n1b2, n2b2, Mt, Wcomb, M3, c1, c3);
  hipLaunchKernelGGL(k_nodegemm, dim3((N_+31)/32), dim3(256), 0, stream,
                     x, sx, tx, eW1, n1W1, AC, Bn);
  hipLaunchKernelGGL(k_estats, dim3(1024), dim3(256), 0, stream, rcs, AC, Bn, estR);
  hipLaunchKernelGGL(k_bnfin, dim3(1), dim3(128), 0, stream, estR, 64, e_g, e_be, se, te, 1.f/(float)E_);
  hipLaunchKernelGGL(k_epass0, dim3(E_/64), dim3(256), 0, stream,
                     rcs, AC, Bn, Mt, se, te, n1R);
  hipLaunchKernelGGL(k_bnfin, dim3(1), dim3(128), 0, stream, n1R, 64, n1_g, n1_be, sn1, tn1, 1.f/(float)E_);
  hipLaunchKernelGGL(k_epass1, dim3(E_/64), dim3(256), 0, stream,
                     rcs, AC, Bn, Mt, se, te, sn1, tn1, aggf);
  hipLaunchKernelGGL(k_n2, dim3((N_+31)/32), dim3(256), 0, stream,
                     x, sx, tx, aggf, invc, Wcomb, c1, counts, hn2, n2R);
  hipLaunchKernelGGL(k_bnfin, dim3(1), dim3(128), 0, stream, n2R, 64, n2_g, n2_be, sn2, tn2, 1.f/(float)N_);
  hipLaunchKernelGGL(k_goff, dim3(1), dim3(256), 0, stream, batch, goff);
  hipLaunchKernelGGL(k_gmean, dim3(256), dim3(128), 0, stream, hn2, goff, sn2, tn2, gmean);
  hipLaunchKernelGGL(k_hg, dim3(128), dim3(256), 0, stream, gmean, M3, c3, goff, hg, gls);
  hipLaunchKernelGGL(k_bnfin, dim3(1), dim3(128), 0, stream, gls, 1, gl_g, gl_be, sgl, tgl, 1.f/(float)G_);
  hipLaunchKernelGGL(k_out, dim3(2), dim3(256), 0, stream, hg, sgl, tgl, glW2, glb2, out);
}

// Round 7
// 1552.139 us; speedup vs baseline: 1.5171x; 1.1926x over previous
//
#include <hip/hip_runtime.h>
#include <hip/hip_bf16.h>
#include <stdint.h>

#define DEV static __device__ __forceinline__

constexpr int N_ = 50000;
constexpr int E_ = 1600000;
constexpr int G_ = 256;

typedef __attribute__((ext_vector_type(8))) short short8;
typedef __attribute__((ext_vector_type(4))) float float4v;

DEV uint16_t f2bf(float f){
  uint32_t u = __float_as_uint(f);
  uint32_t r = (u + 0x7fffu + ((u >> 16) & 1u)) >> 16;
  return (uint16_t)r;
}
DEV float bf2f(uint16_t v){ return __uint_as_float((uint32_t)v << 16); }
DEV void unpack2(uint32_t p, float& a, float& b){
  a = __uint_as_float(p << 16);
  b = __uint_as_float(p & 0xffff0000u);
}
DEV uint32_t pack2(float a, float b){
  return (uint32_t)f2bf(a) | ((uint32_t)f2bf(b) << 16);
}
// 8B-aligned LDS load of 8 bf16 (stride-132 rows are 264B = 8-aligned only).
DEV short8 lds_load8(const uint16_t* p){
  union { short8 v; uint2 u[2]; } c;
  c.u[0] = *(const uint2*)p;
  c.u[1] = *(const uint2*)(p + 4);
  return c.v;
}
DEV void lds_store16B_as8(uint32_t* d, uint4 v){
  *(uint2*)d       = make_uint2(v.x, v.y);
  *(uint2*)(d + 2) = make_uint2(v.z, v.w);
}

// ---------------- x column stats ----------------
__global__ __launch_bounds__(256) void k_xstats(const float* __restrict__ x, float* __restrict__ xstats){
  __shared__ float lst[96];
  int t = threadIdx.x;
  if (t < 96) lst[t] = 0.f;
  __syncthreads();
  int gid = blockIdx.x * 256 + t;
  int c4 = (gid % 12) * 4;
  float s[4] = {0,0,0,0}, q[4] = {0,0,0,0};
  const float4v* x4 = (const float4v*)x;
  for (int i = gid; i < N_ * 12; i += 64512){
    float4v v = x4[i];
    #pragma unroll
    for (int j = 0; j < 4; j++){ s[j] += v[j]; q[j] += v[j]*v[j]; }
  }
  #pragma unroll
  for (int j = 0; j < 4; j++){
    atomicAdd(&lst[c4 + j], s[j]);
    atomicAdd(&lst[48 + c4 + j], q[j]);
  }
  __syncthreads();
  if (t < 96) atomicAdd(&xstats[t], lst[t]);
}

__global__ void k_xfin(const float* __restrict__ xstats, const float* __restrict__ g,
                       const float* __restrict__ b, float* __restrict__ sx, float* __restrict__ tx){
  int c = threadIdx.x;
  if (c < 48){
    float m = xstats[c] / (float)N_;
    float v = xstats[48 + c] / (float)N_ - m*m;
    float s = g[c] / sqrtf(v + 1e-5f);
    sx[c] = s; tx[c] = b[c] - m*s;
  }
}

// ---------------- histogram of col ----------------
__global__ __launch_bounds__(256) void k_hist(const int* __restrict__ ei, int* __restrict__ counts){
  int e = blockIdx.x * 256 + threadIdx.x;
  if (e < E_) atomicAdd(&counts[ei[E_ + e]], 1);
}

// ---------------- 1/count ----------------
__global__ __launch_bounds__(256) void k_invc(const int* __restrict__ counts, float* __restrict__ invc){
  int n = blockIdx.x * 256 + threadIdx.x;
  if (n < N_){ int c = counts[n]; invc[n] = (c > 0) ? 1.f/(float)c : 0.f; }
}

// ---------------- exclusive scan of counts ----------------
__global__ __launch_bounds__(256) void k_scan(const int* __restrict__ counts, int* __restrict__ off, int* __restrict__ cur){
  __shared__ int wsum[4];
  __shared__ int carry_s;
  int t = threadIdx.x, lane = t & 63, w = t >> 6;
  if (t == 0) carry_s = 0;
  __syncthreads();
  for (int base = 0; base < N_; base += 1024){
    int i0 = base + t * 4;
    int v0 = (i0 + 0 < N_) ? counts[i0 + 0] : 0;
    int v1 = (i0 + 1 < N_) ? counts[i0 + 1] : 0;
    int v2 = (i0 + 2 < N_) ? counts[i0 + 2] : 0;
    int v3 = (i0 + 3 < N_) ? counts[i0 + 3] : 0;
    int tsum = v0 + v1 + v2 + v3;
    int xs = tsum;
    for (int d = 1; d < 64; d <<= 1){ int y = __shfl_up(xs, d); if (lane >= d) xs += y; }
    if (lane == 63) wsum[w] = xs;
    __syncthreads();
    int woff = 0;
    for (int k = 0; k < w; k++) woff += wsum[k];
    int excl = xs - tsum + woff + carry_s;
    int e0 = excl, e1 = e0 + v0, e2 = e1 + v1, e3 = e2 + v2;
    if (i0 + 0 < N_){ off[i0+0] = e0; cur[i0+0] = e0; }
    if (i0 + 1 < N_){ off[i0+1] = e1; cur[i0+1] = e1; }
    if (i0 + 2 < N_){ off[i0+2] = e2; cur[i0+2] = e2; }
    if (i0 + 3 < N_){ off[i0+3] = e3; cur[i0+3] = e3; }
    __syncthreads();
    if (t == 0) carry_s += wsum[0] + wsum[1] + wsum[2] + wsum[3];
    __syncthreads();
  }
  if (t == 0) off[N_] = carry_s;
}

// ---------------- counting-sort placement ----------------
__global__ __launch_bounds__(256) void k_place(const int* __restrict__ ei, int* __restrict__ cur,
                                               int2* __restrict__ rcs){
  int e = blockIdx.x * 256 + threadIdx.x;
  if (e < E_){
    int c = ei[E_ + e];
    int p = atomicAdd(&cur[c], 1);
    rcs[p] = make_int2(ei[e], c);
  }
}

// ---------------- weight precomputation ----------------
__global__ __launch_bounds__(256) void k_wprep(
    const float* __restrict__ eW2, const float* __restrict__ n1W1,
    const float* __restrict__ n1W2, const float* __restrict__ n2W1,
    const float* __restrict__ n2W2, const float* __restrict__ glW1,
    const float* __restrict__ n1b2, const float* __restrict__ n2b2,
    uint16_t* __restrict__ Mt, float* __restrict__ Wcomb,
    float* __restrict__ M3, float* __restrict__ c1, float* __restrict__ c3){
  int flat = blockIdx.x * 256 + threadIdx.x;
  if (flat < 16384){
    int n = flat & 127, k = flat >> 7;
    float a = 0.f;
    for (int j = 0; j < 128; j++) a += eW2[k*128 + j] * n1W1[(48 + j)*128 + n];
    Mt[n*128 + k] = f2bf(a);
  } else if (flat < 32768){
    int b = flat - 16384;
    int n = b & 127, j = b >> 7;
    float a = 0.f;
    for (int m = 0; m < 128; m++) a += n1W2[j*128 + m] * n2W1[(48 + m)*128 + n];
    Wcomb[(48 + j)*128 + n] = a;
  } else if (flat < 38912){
    int b = flat - 32768;
    int n = b & 127, k = b >> 7;
    Wcomb[k*128 + n] = n2W1[k*128 + n];
  } else if (flat < 55296){
    int b = flat - 38912;
    int n = b & 127, j = b >> 7;
    float a = 0.f;
    for (int m = 0; m < 128; m++) a += n2W2[j*128 + m] * glW1[m*128 + n];
    M3[j*128 + n] = a;
  } else if (flat < 55552){
    int e = flat - 55296;
    if (e < 128){
      float a = 0.f;
      for (int m = 0; m < 128; m++) a += n1b2[m] * n2W1[(48 + m)*128 + e];
      c1[e] = a;
    } else {
      int n = e - 128;
      float a = 0.f;
      for (int m = 0; m < 128; m++) a += n2b2[m] * glW1[m*128 + n];
      c3[n] = a;
    }
  }
}

// ---------------- node GEMM: A,B,C (bf16) ----------------
__global__ __launch_bounds__(256) void k_nodegemm(
    const float* __restrict__ x, const float* __restrict__ sx, const float* __restrict__ tx,
    const float* __restrict__ eW1, const float* __restrict__ n1W1,
    uint16_t* __restrict__ AC, uint16_t* __restrict__ Bn){
  __shared__ float xT[48][36];
  __shared__ float W[48][128];
  int t = threadIdx.x;
  int n0 = blockIdx.x * 32;
  for (int idx = t; idx < 384; idx += 256){
    int r = idx / 12, q = idx % 12;
    int n = n0 + r;
    float4v v = {0.f,0.f,0.f,0.f};
    if (n < N_) v = *(const float4v*)&x[(size_t)n*48 + q*4];
    #pragma unroll
    for (int i = 0; i < 4; i++){
      int k = q*4 + i;
      xT[k][r] = v[i] * sx[k] + tx[k];
    }
  }
  int cg = t & 31, ng = t >> 5;
  const float* Wsrc0 = eW1;
  const float* Wsrc1 = eW1 + 48*128;
  const float* Wsrc2 = n1W1;
  for (int seg = 0; seg < 3; seg++){
    const float* Wsrc = (seg == 0) ? Wsrc0 : (seg == 1) ? Wsrc1 : Wsrc2;
    __syncthreads();
    {
      const float4v* src4 = (const float4v*)Wsrc;
      float4v* W4 = (float4v*)W;
      for (int idx = t; idx < 1536; idx += 256) W4[idx] = src4[idx];
    }
    __syncthreads();
    float acc[4][4] = {{0.f}};
    #pragma unroll 4
    for (int k = 0; k < 48; k++){
      float4v xv = *(const float4v*)&xT[k][ng*4];
      float4v wv = *(const float4v*)&W[k][cg*4];
      #pragma unroll
      for (int i = 0; i < 4; i++)
        #pragma unroll
        for (int j = 0; j < 4; j++)
          acc[i][j] += xv[i]*wv[j];
    }
    #pragma unroll
    for (int i = 0; i < 4; i++){
      int n = n0 + ng*4 + i;
      if (n >= N_) continue;
      uint2 pv;
      pv.x = pack2(acc[i][0], acc[i][1]);
      pv.y = pack2(acc[i][2], acc[i][3]);
      if (seg == 0)      *(uint2*)&AC[(size_t)n*256 + cg*4] = pv;
      else if (seg == 1) *(uint2*)&Bn[(size_t)n*128 + cg*4] = pv;
      else               *(uint2*)&AC[(size_t)n*256 + 128 + cg*4] = pv;
    }
  }
}

// ---------------- edge BN stats pass (h1e = A[row]+B[col]) ----------------
__global__ __launch_bounds__(256) void k_estats(const int2* __restrict__ rcs,
    const uint16_t* __restrict__ AC, const uint16_t* __restrict__ Bn, float* __restrict__ estR){
  __shared__ float red[4][64][4];
  __shared__ float lst[256];
  int t = threadIdx.x, lane = t & 63, w = t >> 6;
  int wid = blockIdx.x * 4 + w, nw = gridDim.x * 4;
  float s0=0,q0=0,s1=0,q1=0;
  const uint32_t* ACu = (const uint32_t*)AC;
  const uint32_t* Bu  = (const uint32_t*)Bn;
  for (int e = wid; e < E_; e += nw){
    int2 rc = rcs[e];
    uint32_t pa = ACu[(size_t)rc.x*128 + lane];
    uint32_t pb = Bu[(size_t)rc.y*64 + lane];
    float a0,a1,b0,b1; unpack2(pa,a0,a1); unpack2(pb,b0,b1);
    float h0 = a0 + b0, h1 = a1 + b1;
    s0 += h0; q0 += h0*h0; s1 += h1; q1 += h1*h1;
  }
  red[w][lane][0]=s0; red[w][lane][1]=q0; red[w][lane][2]=s1; red[w][lane][3]=q1;
  __syncthreads();
  if (t < 64){
    float S0=0,Q0=0,S1=0,Q1=0;
    for (int ww = 0; ww < 4; ww++){ S0+=red[ww][t][0]; Q0+=red[ww][t][1]; S1+=red[ww][t][2]; Q1+=red[ww][t][3]; }
    lst[2*t] = S0; lst[2*t+1] = S1; lst[128+2*t] = Q0; lst[128+2*t+1] = Q1;
  }
  __syncthreads();
  atomicAdd(&estR[(blockIdx.x & 63)*256 + t], lst[t]);
}

// ---------------- generic BN finalize ----------------
__global__ void k_bnfin(const float* __restrict__ statsR, int reps, const float* __restrict__ g,
                        const float* __restrict__ be, float* __restrict__ s_out, float* __restrict__ t_out,
                        float inv_n){
  int c = threadIdx.x;
  if (c >= 128) return;
  float sm = 0.f, sq = 0.f;
  for (int r = 0; r < reps; r++){ sm += statsR[r*256 + c]; sq += statsR[r*256 + 128 + c]; }
  float m = sm * inv_n;
  float v = sq * inv_n - m*m;
  float s = g[c] / sqrtf(v + 1e-5f);
  s_out[c] = s;
  t_out[c] = be[c] - m*s;
}

// ======== edge MFMA passes: stride 132 shorts (264B rows, 8B-aligned ops only).
// R3-proven structure: Mt staged in LDS (global-direct B regressed — R6),
// batched LDS round-trips in P4 (cross-lane chains neutral, R4/R5).
// 53248 B LDS -> 3 blocks/CU (R3's 136-stride gave 2).

// ---------------- edge MFMA pass 0: h1n stats ----------------
__global__ __launch_bounds__(256) void k_epass0(
    const int2* __restrict__ rcs,
    const uint16_t* __restrict__ AC, const uint16_t* __restrict__ Bn,
    const uint16_t* __restrict__ Mt, const float* __restrict__ se, const float* __restrict__ te,
    float* __restrict__ n1R){
  __shared__ __align__(16) uint16_t bufA[64*132];   // relu tile -> C tile
  __shared__ __align__(16) uint16_t bufB[128*132];  // Mt -> h tile (rows 0..63)
  __shared__ __align__(16) float sete[256];         // se | te
  __shared__ float lst[256];
  __shared__ int srow[64], scol[64];
  const int t = threadIdx.x;
  const long i0 = (long)blockIdx.x * 64;
  const int lane = t & 63, w = t >> 6;
  const int m = lane & 15, quad = lane >> 4;

  if (t < 128){ sete[t] = se[t]; sete[128 + t] = te[t]; }
  lst[t] = 0.f;
  if (t < 64){ int2 rc = rcs[i0 + t]; srow[t] = rc.x; scol[t] = rc.y; }
  __syncthreads();

  // P0: stage relu_e into bufA
  {
    int e = t >> 2, q = t & 3;
    int r = srow[e], c = scol[e];
    const uint4* Ap = (const uint4*)((const uint32_t*)AC + (size_t)r*128 + q*16);
    const uint4* Bp = (const uint4*)((const uint32_t*)Bn + (size_t)c*64  + q*16);
    uint32_t* dstd = (uint32_t*)bufA + e*66 + q*16;
    int cb = q*32;
    #pragma unroll
    for (int u = 0; u < 4; u++){
      uint4 va = Ap[u], vb = Bp[u];
      float4v sA = *(const float4v*)&sete[cb + u*8];
      float4v sB = *(const float4v*)&sete[cb + u*8 + 4];
      float4v tA = *(const float4v*)&sete[128 + cb + u*8];
      float4v tB = *(const float4v*)&sete[128 + cb + u*8 + 4];
      float a0,a1,b0,b1; uint4 o;
      unpack2(va.x,a0,a1); unpack2(vb.x,b0,b1);
      o.x = pack2(fmaxf(0.f,(a0+b0)*sA[0]+tA[0]), fmaxf(0.f,(a1+b1)*sA[1]+tA[1]));
      unpack2(va.y,a0,a1); unpack2(vb.y,b0,b1);
      o.y = pack2(fmaxf(0.f,(a0+b0)*sA[2]+tA[2]), fmaxf(0.f,(a1+b1)*sA[3]+tA[3]));
      unpack2(va.z,a0,a1); unpack2(vb.z,b0,b1);
      o.z = pack2(fmaxf(0.f,(a0+b0)*sB[0]+tB[0]), fmaxf(0.f,(a1+b1)*sB[1]+tB[1]));
      unpack2(va.w,a0,a1); unpack2(vb.w,b0,b1);
      o.w = pack2(fmaxf(0.f,(a0+b0)*sB[2]+tB[2]), fmaxf(0.f,(a1+b1)*sB[3]+tB[3]));
      lds_store16B_as8(dstd + u*4, o);
    }
  }
  // P1: stage Mt into bufB
  {
    int n = t >> 1, h = t & 1;
    const uint4* src = (const uint4*)((const uint32_t*)Mt + n*64 + h*32);
    uint32_t* dstd = (uint32_t*)bufB + n*66 + h*32;
    #pragma unroll
    for (int u = 0; u < 8; u++) lds_store16B_as8(dstd + u*4, src[u]);
  }
  __syncthreads();

  // P2: MFMA — 16 edges/wave x 128 cols, K=128
  float4v acc[8];
  #pragma unroll
  for (int nt = 0; nt < 8; nt++){ acc[nt][0]=0.f; acc[nt][1]=0.f; acc[nt][2]=0.f; acc[nt][3]=0.f; }
  {
    const uint16_t* aptr = bufA + (w*16 + m)*132 + quad*8;
    const uint16_t* bbase = bufB + m*132 + quad*8;
    #pragma unroll
    for (int ks = 0; ks < 4; ks++){
      short8 af = lds_load8(aptr + ks*32);
      #pragma unroll
      for (int nt = 0; nt < 8; nt++){
        short8 bf = lds_load8(bbase + nt*16*132 + ks*32);
        acc[nt] = __builtin_amdgcn_mfma_f32_16x16x32_bf16(af, bf, acc[nt], 0, 0, 0);
      }
    }
  }
  __syncthreads();

  // P3: stage C tile into bufA; write acc as bf16 into bufB rows 0..63
  {
    int e = t >> 2, q = t & 3;
    int r = srow[e];
    const uint4* src = (const uint4*)((const uint32_t*)AC + (size_t)r*128 + 64 + q*16);
    uint32_t* dstd = (uint32_t*)bufA + e*66 + q*16;
    #pragma unroll
    for (int u = 0; u < 4; u++) lds_store16B_as8(dstd + u*4, src[u]);
  }
  #pragma unroll
  for (int nt = 0; nt < 8; nt++)
    #pragma unroll
    for (int reg = 0; reg < 4; reg++)
      bufB[(w*16 + quad*4 + reg)*132 + nt*16 + m] = f2bf(acc[nt][reg]);
  __syncthreads();

  // P4: h = acc + C, batched stats
  {
    int cp = t & 63, eg = t >> 6;
    float ss0=0,qq0=0,ss1=0,qq1=0;
    #pragma unroll
    for (int it = 0; it < 16; it++){
      int e = it*4 + eg;
      uint32_t ph = ((uint32_t*)bufB)[e*66 + cp];
      uint32_t pc = ((uint32_t*)bufA)[e*66 + cp];
      float h0,h1,c0,c1v;
      unpack2(ph,h0,h1); unpack2(pc,c0,c1v);
      float v0 = h0 + c0, v1 = h1 + c1v;
      ss0 += v0; qq0 += v0*v0; ss1 += v1; qq1 += v1*v1;
    }
    atomicAdd(&lst[2*cp], ss0);
    atomicAdd(&lst[2*cp+1], ss1);
    atomicAdd(&lst[128+2*cp], qq0);
    atomicAdd(&lst[128+2*cp+1], qq1);
  }
  __syncthreads();
  atomicAdd(&n1R[(blockIdx.x & 63)*256 + t], lst[t]);
}

// ---------------- edge MFMA pass 1: recompute, BN(n1)+relu, segment-aggregate ----------------
__global__ __launch_bounds__(256) void k_epass1(
    const int2* __restrict__ rcs,
    const uint16_t* __restrict__ AC, const uint16_t* __restrict__ Bn,
    const uint16_t* __restrict__ Mt, const float* __restrict__ se, const float* __restrict__ te,
    const float* __restrict__ sn1, const float* __restrict__ tn1,
    float* __restrict__ aggf){
  __shared__ __align__(16) uint16_t bufA[64*132];   // relu tile -> C tile
  __shared__ __align__(16) uint16_t bufB[128*132];  // Mt -> h tile (rows 0..63) + scratch (rows 64+)
  __shared__ __align__(16) float sete[256];         // se | te
  __shared__ int srow[64], scol[64];
  __shared__ int snseg;
  const int t = threadIdx.x;
  const long i0 = (long)blockIdx.x * 64;
  const int lane = t & 63, w = t >> 6;
  const int m = lane & 15, quad = lane >> 4;

  // post-MFMA scratch carved from bufB rows 64..127 (dword offsets; h tile = dwords [0,4224))
  uint32_t* bufBu = (uint32_t*)bufB;
  float* segacc  = (float*)(bufBu + 4224);   // 24*128 floats -> [4224,7296)
  float* sn1c    = (float*)(bufBu + 7296);   // 128
  float* tn1c    = (float*)(bufBu + 7424);   // 128
  int*   ssid_s  = (int*)(bufBu + 7552);     // 64
  int*   scseg_s = (int*)(bufBu + 7616);     // 64

  if (t < 128){ sete[t] = se[t]; sete[128 + t] = te[t]; }
  if (t < 64){ int2 rc = rcs[i0 + t]; srow[t] = rc.x; scol[t] = rc.y; }
  __syncthreads();

  // P0: stage relu_e into bufA
  {
    int e = t >> 2, q = t & 3;
    int r = srow[e], c = scol[e];
    const uint4* Ap = (const uint4*)((const uint32_t*)AC + (size_t)r*128 + q*16);
    const uint4* Bp = (const uint4*)((const uint32_t*)Bn + (size_t)c*64  + q*16);
    uint32_t* dstd = (uint32_t*)bufA + e*66 + q*16;
    int cb = q*32;
    #pragma unroll
    for (int u = 0; u < 4; u++){
      uint4 va = Ap[u], vb = Bp[u];
      float4v sA = *(const float4v*)&sete[cb + u*8];
      float4v sB = *(const float4v*)&sete[cb + u*8 + 4];
      float4v tA = *(const float4v*)&sete[128 + cb + u*8];
      float4v tB = *(const float4v*)&sete[128 + cb + u*8 + 4];
      float a0,a1,b0,b1; uint4 o;
      unpack2(va.x,a0,a1); unpack2(vb.x,b0,b1);
      o.x = pack2(fmaxf(0.f,(a0+b0)*sA[0]+tA[0]), fmaxf(0.f,(a1+b1)*sA[1]+tA[1]));
      unpack2(va.y,a0,a1); unpack2(vb.y,b0,b1);
      o.y = pack2(fmaxf(0.f,(a0+b0)*sA[2]+tA[2]), fmaxf(0.f,(a1+b1)*sA[3]+tA[3]));
      unpack2(va.z,a0,a1); unpack2(vb.z,b0,b1);
      o.z = pack2(fmaxf(0.f,(a0+b0)*sB[0]+tB[0]), fmaxf(0.f,(a1+b1)*sB[1]+tB[1]));
      unpack2(va.w,a0,a1); unpack2(vb.w,b0,b1);
      o.w = pack2(fmaxf(0.f,(a0+b0)*sB[2]+tB[2]), fmaxf(0.f,(a1+b1)*sB[3]+tB[3]));
      lds_store16B_as8(dstd + u*4, o);
    }
  }
  // P1: stage Mt into bufB
  {
    int n = t >> 1, h = t & 1;
    const uint4* src = (const uint4*)((const uint32_t*)Mt + n*64 + h*32);
    uint32_t* dstd = bufBu + n*66 + h*32;
    #pragma unroll
    for (int u = 0; u < 8; u++) lds_store16B_as8(dstd + u*4, src[u]);
  }
  __syncthreads();

  // P2: MFMA
  float4v acc[8];
  #pragma unroll
  for (int nt = 0; nt < 8; nt++){ acc[nt][0]=0.f; acc[nt][1]=0.f; acc[nt][2]=0.f; acc[nt][3]=0.f; }
  {
    const uint16_t* aptr = bufA + (w*16 + m)*132 + quad*8;
    const uint16_t* bbase = bufB + m*132 + quad*8;
    #pragma unroll
    for (int ks = 0; ks < 4; ks++){
      short8 af = lds_load8(aptr + ks*32);
      #pragma unroll
      for (int nt = 0; nt < 8; nt++){
        short8 bf = lds_load8(bbase + nt*16*132 + ks*32);
        acc[nt] = __builtin_amdgcn_mfma_f32_16x16x32_bf16(af, bf, acc[nt], 0, 0, 0);
      }
    }
  }
  __syncthreads();

  // P3: C tile into bufA; raw acc (bf16) into bufB rows 0..63; scratch setup in rows 64+
  {
    int e = t >> 2, q = t & 3;
    int r = srow[e];
    const uint4* src = (const uint4*)((const uint32_t*)AC + (size_t)r*128 + 64 + q*16);
    uint32_t* dstd = (uint32_t*)bufA + e*66 + q*16;
    #pragma unroll
    for (int u = 0; u < 4; u++) lds_store16B_as8(dstd + u*4, src[u]);
  }
  #pragma unroll
  for (int nt = 0; nt < 8; nt++)
    #pragma unroll
    for (int reg = 0; reg < 4; reg++)
      bufB[(w*16 + quad*4 + reg)*132 + nt*16 + m] = f2bf(acc[nt][reg]);
  if (t < 64){
    bool bnd = (t > 0) && (scol[t] != scol[t-1]);
    unsigned long long mask = __ballot(bnd);
    int sid = __popcll(mask << (63 - t));
    ssid_s[t] = sid;
    if (bnd || t == 0) scseg_s[sid] = scol[t];
    if (t == 63) snseg = sid + 1;
  } else if (t < 192){
    int c = t - 64;
    sn1c[c] = sn1[c]; tn1c[c] = tn1[c];
  }
  for (int i = t; i < 24*128; i += 256) segacc[i] = 0.f;
  __syncthreads();

  // P4: BN+relu on the fly, batched segment walk
  {
    int cp = t & 63, eg = t >> 6;
    float s0 = sn1c[2*cp], s1 = sn1c[2*cp+1];
    float b0 = tn1c[2*cp], b1 = tn1c[2*cp+1];
    int nseg = snseg;
    bool lp = (nseg <= 24);
    int cursid = ssid_s[eg*16];
    float r0 = 0.f, r1 = 0.f;
    for (int it = 0; it < 16; it++){
      int e = eg*16 + it;
      uint32_t ph = bufBu[e*66 + cp];
      uint32_t pc = ((uint32_t*)bufA)[e*66 + cp];
      float h0,h1,c0,c1v;
      unpack2(ph,h0,h1); unpack2(pc,c0,c1v);
      float v0 = fmaxf(0.f, (h0+c0)*s0 + b0);
      float v1 = fmaxf(0.f, (h1+c1v)*s1 + b1);
      int sid = ssid_s[e];
      if (sid != cursid){
        if (lp){ atomicAdd(&segacc[cursid*128 + 2*cp], r0); atomicAdd(&segacc[cursid*128 + 2*cp+1], r1); }
        else { int c = scseg_s[cursid];
               atomicAdd(&aggf[(size_t)c*128 + 2*cp], r0); atomicAdd(&aggf[(size_t)c*128 + 2*cp+1], r1); }
        cursid = sid; r0 = 0.f; r1 = 0.f;
      }
      r0 += v0; r1 += v1;
    }
    if (lp){ atomicAdd(&segacc[cursid*128 + 2*cp], r0); atomicAdd(&segacc[cursid*128 + 2*cp+1], r1); }
    else { int c = scseg_s[cursid];
           atomicAdd(&aggf[(size_t)c*128 + 2*cp], r0); atomicAdd(&aggf[(size_t)c*128 + 2*cp+1], r1); }
    __syncthreads();
    if (lp){
      for (int idx = t; idx < nseg*64; idx += 256){
        int s = idx >> 6, cpp = idx & 63;
        float v0 = segacc[s*128 + 2*cpp], v1 = segacc[s*128 + 2*cpp+1];
        int c = scseg_s[s];
        float* dst = &aggf[(size_t)c*128 + 2*cpp];
        if (s == 0 || s == nseg - 1){ atomicAdd(dst, v0); atomicAdd(dst+1, v1); }
        else { dst[0] = v0; dst[1] = v1; }   // middle col wholly owned by this block
      }
    }
  }
}

// ---------------- n2 GEMM ----------------
__global__ __launch_bounds__(256) void k_n2(const float* __restrict__ x,
    const float* __restrict__ sx, const float* __restrict__ tx,
    const float* __restrict__ aggf, const float* __restrict__ invc,
    const float* __restrict__ Wc, const float* __restrict__ c1, const int* __restrict__ counts,
    float* __restrict__ hn2, float* __restrict__ n2R){
  __shared__ float xT[44][36];
  __shared__ float wT[44][128];
  __shared__ float lst[256];
  int t = threadIdx.x;
  int n0 = blockIdx.x * 32;
  int cg = t & 31, ng = t >> 5;
  lst[t] = 0.f;
  float acc[4][4] = {{0.f}};
  for (int kc = 0; kc < 176; kc += 44){
    __syncthreads();
    for (int idx = t; idx < 32*44; idx += 256){
      int r = idx / 44, k = idx % 44;
      int n = n0 + r, kk = kc + k;
      float v = 0.f;
      if (n < N_){
        if (kk < 48) v = x[(size_t)n*48 + kk] * sx[kk] + tx[kk];
        else         v = aggf[(size_t)n*128 + (kk - 48)] * invc[n];
      }
      xT[k][r] = v;
    }
    for (int idx = t; idx < 44*128; idx += 256){
      int k = idx >> 7, c = idx & 127;
      wT[k][c] = Wc[(kc + k)*128 + c];
    }
    __syncthreads();
    for (int k = 0; k < 44; k++){
      float4v xv = *(const float4v*)&xT[k][ng*4];
      float4v wv = *(const float4v*)&wT[k][cg*4];
      #pragma unroll
      for (int i = 0; i < 4; i++)
        #pragma unroll
        for (int j = 0; j < 4; j++)
          acc[i][j] += xv[i]*wv[j];
    }
  }
  float csum[4] = {0,0,0,0}, cqs[4] = {0,0,0,0};
  for (int i = 0; i < 4; i++){
    int n = n0 + ng*4 + i;
    if (n >= N_) continue;
    bool ok = counts[n] > 0;
    float4v o;
    #pragma unroll
    for (int j = 0; j < 4; j++){
      float vv = acc[i][j] + (ok ? c1[cg*4 + j] : 0.f);
      o[j] = vv; csum[j] += vv; cqs[j] += vv*vv;
    }
    *(float4v*)&hn2[(size_t)n*128 + cg*4] = o;
  }
  #pragma unroll
  for (int j = 0; j < 4; j++){
    atomicAdd(&lst[cg*4 + j], csum[j]);
    atomicAdd(&lst[128 + cg*4 + j], cqs[j]);
  }
  __syncthreads();
  atomicAdd(&n2R[(blockIdx.x & 63)*256 + t], lst[t]);
}

// ---------------- graph offsets from sorted batch ----------------
__global__ void k_goff(const int* __restrict__ batch, int* __restrict__ goff){
  int g = threadIdx.x;
  int lo = 0, hi = N_;
  while (lo < hi){ int mid = (lo + hi) >> 1; if (batch[mid] < g) lo = mid + 1; else hi = mid; }
  goff[g] = lo;
  if (g == 0) goff[256] = N_;
}

// ---------------- per-graph mean of relu(bn(h_n2)) ----------------
__global__ __launch_bounds__(128) void k_gmean(const float* __restrict__ hn2, const int* __restrict__ goff,
    const float* __restrict__ sn2, const float* __restrict__ tn2, float* __restrict__ gmean){
  int g = blockIdx.x, c = threadIdx.x;
  int b = goff[g], e = goff[g+1];
  float s = sn2[c], tt = tn2[c], a = 0.f;
  for (int r = b; r < e; r++) a += fmaxf(0.f, hn2[(size_t)r*128 + c]*s + tt);
  gmean[g*128 + c] = (e > b) ? a/(float)(e - b) : 0.f;
}

// ---------------- hg = gmean@M3 + cond*c3, gl stats ----------------
__global__ __launch_bounds__(256) void k_hg(const float* __restrict__ gmean, const float* __restrict__ M3,
    const float* __restrict__ c3, const int* __restrict__ goff,
    float* __restrict__ hg, float* __restrict__ gls){
  int idx = blockIdx.x * 256 + threadIdx.x;
  int g = idx >> 7, c = idx & 127;
  float a = 0.f;
  for (int k = 0; k < 128; k++) a += gmean[g*128 + k] * M3[k*128 + c];
  if (goff[g+1] > goff[g]) a += c3[c];
  hg[idx] = a;
  atomicAdd(&gls[c], a);
  atomicAdd(&gls[128 + c], a*a);
}

// ---------------- final output ----------------
__global__ __launch_bounds__(256) void k_out(const float* __restrict__ hg, const float* __restrict__ sgl,
    const float* __restrict__ tgl, const float* __restrict__ glW2, const float* __restrict__ glb2,
    float* __restrict__ out){
  int idx = blockIdx.x * 256 + threadIdx.x;
  int g = idx >> 1, o = idx & 1;
  float a = 0.f;
  for (int c = 0; c < 128; c++){
    float r = fmaxf(0.f, hg[g*128 + c]*sgl[c] + tgl[c]);
    a += r * glW2[c*2 + o];
  }
  out[idx] = a + glb2[o];
}

extern "C" void kernel_launch(void* const* d_in, const int* in_sizes, int n_in,
                              void* d_out, int out_size, void* d_ws, size_t ws_size,
                              hipStream_t stream){
  const float* x     = (const float*)d_in[0];
  const int*   ei    = (const int*)d_in[1];
  const int*   batch = (const int*)d_in[2];
  const float* bn_g  = (const float*)d_in[3];
  const float* bn_b  = (const float*)d_in[4];
  const float* eW1   = (const float*)d_in[5];
  const float* e_g   = (const float*)d_in[7];
  const float* e_be  = (const float*)d_in[8];
  const float* eW2   = (const float*)d_in[9];
  const float* n1W1  = (const float*)d_in[11];
  const float* n1_g  = (const float*)d_in[13];
  const float* n1_be = (const float*)d_in[14];
  const float* n1W2  = (const float*)d_in[15];
  const float* n1b2  = (const float*)d_in[16];
  const float* n2W1  = (const float*)d_in[17];
  const float* n2_g  = (const float*)d_in[19];
  const float* n2_be = (const float*)d_in[20];
  const float* n2W2  = (const float*)d_in[21];
  const float* n2b2  = (const float*)d_in[22];
  const float* glW1  = (const float*)d_in[23];
  const float* gl_g  = (const float*)d_in[25];
  const float* gl_be = (const float*)d_in[26];
  const float* glW2  = (const float*)d_in[27];
  const float* glb2  = (const float*)d_in[28];
  float* out = (float*)d_out;

  char* w = (char*)d_ws;
  size_t off = 0;
  auto take = [&](size_t bytes) -> char* {
    char* p = w + off;
    off = (off + bytes + 511) & ~(size_t)511;
    return p;
  };

  const size_t ZONE_WORDS = 96 + 3*64*256 + 256 + N_;
  float* zone   = (float*)take(ZONE_WORDS * 4);
  float* xstats = zone;
  float* estR   = zone + 96;
  float* n1R    = zone + 96 + 64*256;
  float* n2R    = zone + 96 + 2*64*256;
  float* gls    = zone + 96 + 3*64*256;
  int*   counts = (int*)(zone + 96 + 3*64*256 + 256);

  float* sx = (float*)take(48*4);   float* tx = (float*)take(48*4);
  float* se = (float*)take(128*4);  float* te = (float*)take(128*4);
  float* sn1 = (float*)take(128*4); float* tn1 = (float*)take(128*4);
  float* sn2 = (float*)take(128*4); float* tn2 = (float*)take(128*4);
  float* sgl = (float*)take(128*4); float* tgl = (float*)take(128*4);
  float* c1 = (float*)take(128*4);  float* c3 = (float*)take(128*4);
  float* invc  = (float*)take((size_t)N_*4);
  float* Wcomb = (float*)take(176*128*4);
  float* M3    = (float*)take(128*128*4);
  float* gmean = (float*)take(G_*128*4);
  float* hg    = (float*)take(G_*128*4);
  int* offs = (int*)take((N_+1)*4);
  int* cur  = (int*)take(N_*4);
  int* goff = (int*)take(257*4);
  uint16_t* Mt = (uint16_t*)take(128*128*2);
  uint16_t* AC = (uint16_t*)take((size_t)N_*256*2);
  uint16_t* Bn = (uint16_t*)take((size_t)N_*128*2);
  float* aggf  = (float*)take((size_t)N_*128*4);
  float* hn2   = (float*)take((size_t)N_*128*4);
  int2* rcs = (int2*)take((size_t)E_*8);

  if (off > ws_size) return;   // clean fail, no fault

  hipMemsetAsync(zone, 0, ZONE_WORDS*4, stream);
  hipMemsetAsync(aggf, 0, (size_t)N_*128*4, stream);

  hipLaunchKernelGGL(k_xstats, dim3(252), dim3(256), 0, stream, x, xstats);
  hipLaunchKernelGGL(k_hist, dim3((E_+255)/256), dim3(256), 0, stream, ei, counts);
  hipLaunchKernelGGL(k_xfin, dim3(1), dim3(64), 0, stream, xstats, bn_g, bn_b, sx, tx);
  hipLaunchKernelGGL(k_scan, dim3(1), dim3(256), 0, stream, counts, offs, cur);
  hipLaunchKernelGGL(k_place, dim3((E_+255)/256), dim3(256), 0, stream, ei, cur, rcs);
  hipLaunchKernelGGL(k_invc, dim3((N_+255)/256), dim3(256), 0, stream, counts, invc);
  hipLaunchKernelGGL(k_wprep, dim3(217), dim3(256), 0, stream,
                     eW2, n1W1, n1W2, n2W1, n2W2, glW1, n1b2, n2b2, Mt, Wcomb, M3, c1, c3);
  hipLaunchKernelGGL(k_nodegemm, dim3((N_+31)/32), dim3(256), 0, stream,
                     x, sx, tx, eW1, n1W1, AC, Bn);
  hipLaunchKernelGGL(k_estats, dim3(1024), dim3(256), 0, stream, rcs, AC, Bn, estR);
  hipLaunchKernelGGL(k_bnfin, dim3(1), dim3(128), 0, stream, estR, 64, e_g, e_be, se, te, 1.f/(float)E_);
  hipLaunchKernelGGL(k_epass0, dim3(E_/64), dim3(256), 0, stream,
                     rcs, AC, Bn, Mt, se, te, n1R);
  hipLaunchKernelGGL(k_bnfin, dim3(1), dim3(128), 0, stream, n1R, 64, n1_g, n1_be, sn1, tn1, 1.f/(float)E_);
  hipLaunchKernelGGL(k_epass1, dim3(E_/64), dim3(256), 0, stream,
                     rcs, AC, Bn, Mt, se, te, sn1, tn1, aggf);
  hipLaunchKernelGGL(k_n2, dim3((N_+31)/32), dim3(256), 0, stream,
                     x, sx, tx, aggf, invc, Wcomb, c1, counts, hn2, n2R);
  hipLaunchKernelGGL(k_bnfin, dim3(1), dim3(128), 0, stream, n2R, 64, n2_g, n2_be, sn2, tn2, 1.f/(float)N_);
  hipLaunchKernelGGL(k_goff, dim3(1), dim3(256), 0, stream, batch, goff);
  hipLaunchKernelGGL(k_gmean, dim3(256), dim3(128), 0, stream, hn2, goff, sn2, tn2, gmean);
  hipLaunchKernelGGL(k_hg, dim3(128), dim3(256), 0, stream, gmean, M3, c3, goff, hg, gls);
  hipLaunchKernelGGL(k_bnfin, dim3(1), dim3(128), 0, stream, gls, 1, gl_g, gl_be, sgl, tgl, 1.f/(float)G_);
  hipLaunchKernelGGL(k_out, dim3(2), dim3(256), 0, stream, hg, sgl, tgl, glW2, glb2, out);
}

// Round 8
// 1524.205 us; speedup vs baseline: 1.5449x; 1.0183x over previous
//
#include <hip/hip_runtime.h>
#include <hip/hip_bf16.h>
#include <stdint.h>

#define DEV static __device__ __forceinline__

constexpr int N_ = 50000;
constexpr int E_ = 1600000;
constexpr int G_ = 256;

typedef __attribute__((ext_vector_type(8))) short short8;
typedef __attribute__((ext_vector_type(4))) float float4v;

DEV uint16_t f2bf(float f){
  uint32_t u = __float_as_uint(f);
  uint32_t r = (u + 0x7fffu + ((u >> 16) & 1u)) >> 16;
  return (uint16_t)r;
}
DEV float bf2f(uint16_t v){ return __uint_as_float((uint32_t)v << 16); }
DEV void unpack2(uint32_t p, float& a, float& b){
  a = __uint_as_float(p << 16);
  b = __uint_as_float(p & 0xffff0000u);
}
DEV uint32_t pack2(float a, float b){
  return (uint32_t)f2bf(a) | ((uint32_t)f2bf(b) << 16);
}
// 8B-aligned LDS ops (stride-132 rows are 264B = 8B-aligned only; R7-proven).
DEV short8 lds_load8(const uint16_t* p){
  union { short8 v; uint2 u[2]; } c;
  c.u[0] = *(const uint2*)p;
  c.u[1] = *(const uint2*)(p + 4);
  return c.v;
}
DEV void lds_store16B_as8(uint32_t* d, uint4 v){
  *(uint2*)d       = make_uint2(v.x, v.y);
  *(uint2*)(d + 2) = make_uint2(v.z, v.w);
}

// ---------------- x column stats ----------------
__global__ __launch_bounds__(256) void k_xstats(const float* __restrict__ x, float* __restrict__ xstats){
  __shared__ float lst[96];
  int t = threadIdx.x;
  if (t < 96) lst[t] = 0.f;
  __syncthreads();
  int gid = blockIdx.x * 256 + t;
  int c4 = (gid % 12) * 4;
  float s[4] = {0,0,0,0}, q[4] = {0,0,0,0};
  const float4v* x4 = (const float4v*)x;
  for (int i = gid; i < N_ * 12; i += 64512){
    float4v v = x4[i];
    #pragma unroll
    for (int j = 0; j < 4; j++){ s[j] += v[j]; q[j] += v[j]*v[j]; }
  }
  #pragma unroll
  for (int j = 0; j < 4; j++){
    atomicAdd(&lst[c4 + j], s[j]);
    atomicAdd(&lst[48 + c4 + j], q[j]);
  }
  __syncthreads();
  if (t < 96) atomicAdd(&xstats[t], lst[t]);
}

__global__ void k_xfin(const float* __restrict__ xstats, const float* __restrict__ g,
                       const float* __restrict__ b, float* __restrict__ sx, float* __restrict__ tx){
  int c = threadIdx.x;
  if (c < 48){
    float m = xstats[c] / (float)N_;
    float v = xstats[48 + c] / (float)N_ - m*m;
    float s = g[c] / sqrtf(v + 1e-5f);
    sx[c] = s; tx[c] = b[c] - m*s;
  }
}

// ---------------- histogram of col ----------------
__global__ __launch_bounds__(256) void k_hist(const int* __restrict__ ei, int* __restrict__ counts){
  int e = blockIdx.x * 256 + threadIdx.x;
  if (e < E_) atomicAdd(&counts[ei[E_ + e]], 1);
}

// ---------------- 1/count ----------------
__global__ __launch_bounds__(256) void k_invc(const int* __restrict__ counts, float* __restrict__ invc){
  int n = blockIdx.x * 256 + threadIdx.x;
  if (n < N_){ int c = counts[n]; invc[n] = (c > 0) ? 1.f/(float)c : 0.f; }
}

// ---------------- two-level scan (replaces single-block k_scan) ----------------
__global__ __launch_bounds__(256) void k_scanA(const int* __restrict__ counts, int* __restrict__ bsum){
  __shared__ int ws[4];
  int b = blockIdx.x, t = threadIdx.x, lane = t & 63, w = t >> 6;
  int i0 = b*1024 + t*4;
  int s = 0;
  #pragma unroll
  for (int j = 0; j < 4; j++){ int i = i0 + j; if (i < N_) s += counts[i]; }
  for (int d = 1; d < 64; d <<= 1) s += __shfl_xor(s, d);
  if (lane == 0) ws[w] = s;
  __syncthreads();
  if (t == 0) bsum[b] = ws[0] + ws[1] + ws[2] + ws[3];
}
__global__ void k_scanB(const int* __restrict__ bsum, int* __restrict__ boff, int* __restrict__ off, int nb){
  int t = threadIdx.x;
  int v = (t < nb) ? bsum[t] : 0;
  int x = v;
  for (int d = 1; d < 64; d <<= 1){ int y = __shfl_up(x, d); if (t >= d) x += y; }
  if (t < nb) boff[t] = x - v;
  if (t == 63) off[N_] = x;
}
__global__ __launch_bounds__(256) void k_scanC(const int* __restrict__ counts, const int* __restrict__ boff,
                                               int* __restrict__ off, int* __restrict__ cur){
  __shared__ int ws[4];
  int b = blockIdx.x, t = threadIdx.x, lane = t & 63, w = t >> 6;
  int i0 = b*1024 + t*4;
  int v0 = (i0+0 < N_) ? counts[i0+0] : 0;
  int v1 = (i0+1 < N_) ? counts[i0+1] : 0;
  int v2 = (i0+2 < N_) ? counts[i0+2] : 0;
  int v3 = (i0+3 < N_) ? counts[i0+3] : 0;
  int ts = v0+v1+v2+v3, xs = ts;
  for (int d = 1; d < 64; d <<= 1){ int y = __shfl_up(xs, d); if (lane >= d) xs += y; }
  if (lane == 63) ws[w] = xs;
  __syncthreads();
  int woff = 0;
  for (int k = 0; k < w; k++) woff += ws[k];
  int excl = xs - ts + woff + boff[b];
  int e0 = excl, e1 = e0+v0, e2 = e1+v1, e3 = e2+v2;
  if (i0+0 < N_){ off[i0+0] = e0; cur[i0+0] = e0; }
  if (i0+1 < N_){ off[i0+1] = e1; cur[i0+1] = e1; }
  if (i0+2 < N_){ off[i0+2] = e2; cur[i0+2] = e2; }
  if (i0+3 < N_){ off[i0+3] = e3; cur[i0+3] = e3; }
}

// ---------------- counting-sort placement ----------------
__global__ __launch_bounds__(256) void k_place(const int* __restrict__ ei, int* __restrict__ cur,
                                               int2* __restrict__ rcs){
  int e = blockIdx.x * 256 + threadIdx.x;
  if (e < E_){
    int c = ei[E_ + e];
    int p = atomicAdd(&cur[c], 1);
    rcs[p] = make_int2(ei[e], c);
  }
}

// ---------------- weight precomputation ----------------
__global__ __launch_bounds__(256) void k_wprep(
    const float* __restrict__ eW2, const float* __restrict__ n1W1,
    const float* __restrict__ n1W2, const float* __restrict__ n2W1,
    const float* __restrict__ n2W2, const float* __restrict__ glW1,
    const float* __restrict__ n1b2, const float* __restrict__ n2b2,
    uint16_t* __restrict__ Mt, float* __restrict__ Wcomb,
    float* __restrict__ M3, float* __restrict__ c1, float* __restrict__ c3){
  int flat = blockIdx.x * 256 + threadIdx.x;
  if (flat < 16384){
    int n = flat & 127, k = flat >> 7;
    float a = 0.f;
    for (int j = 0; j < 128; j++) a += eW2[k*128 + j] * n1W1[(48 + j)*128 + n];
    Mt[n*128 + k] = f2bf(a);
  } else if (flat < 32768){
    int b = flat - 16384;
    int n = b & 127, j = b >> 7;
    float a = 0.f;
    for (int m = 0; m < 128; m++) a += n1W2[j*128 + m] * n2W1[(48 + m)*128 + n];
    Wcomb[(48 + j)*128 + n] = a;
  } else if (flat < 38912){
    int b = flat - 32768;
    int n = b & 127, k = b >> 7;
    Wcomb[k*128 + n] = n2W1[k*128 + n];
  } else if (flat < 55296){
    int b = flat - 38912;
    int n = b & 127, j = b >> 7;
    float a = 0.f;
    for (int m = 0; m < 128; m++) a += n2W2[j*128 + m] * glW1[m*128 + n];
    M3[j*128 + n] = a;
  } else if (flat < 55552){
    int e = flat - 55296;
    if (e < 128){
      float a = 0.f;
      for (int m = 0; m < 128; m++) a += n1b2[m] * n2W1[(48 + m)*128 + e];
      c1[e] = a;
    } else {
      int n = e - 128;
      float a = 0.f;
      for (int m = 0; m < 128; m++) a += n2b2[m] * glW1[m*128 + n];
      c3[n] = a;
    }
  }
}

// ---------------- node GEMM: A,B,C (bf16) ----------------
__global__ __launch_bounds__(256) void k_nodegemm(
    const float* __restrict__ x, const float* __restrict__ sx, const float* __restrict__ tx,
    const float* __restrict__ eW1, const float* __restrict__ n1W1,
    uint16_t* __restrict__ AC, uint16_t* __restrict__ Bn){
  __shared__ float xT[48][36];
  __shared__ float W[48][128];
  int t = threadIdx.x;
  int n0 = blockIdx.x * 32;
  for (int idx = t; idx < 384; idx += 256){
    int r = idx / 12, q = idx % 12;
    int n = n0 + r;
    float4v v = {0.f,0.f,0.f,0.f};
    if (n < N_) v = *(const float4v*)&x[(size_t)n*48 + q*4];
    #pragma unroll
    for (int i = 0; i < 4; i++){
      int k = q*4 + i;
      xT[k][r] = v[i] * sx[k] + tx[k];
    }
  }
  int cg = t & 31, ng = t >> 5;
  const float* Wsrc0 = eW1;
  const float* Wsrc1 = eW1 + 48*128;
  const float* Wsrc2 = n1W1;
  for (int seg = 0; seg < 3; seg++){
    const float* Wsrc = (seg == 0) ? Wsrc0 : (seg == 1) ? Wsrc1 : Wsrc2;
    __syncthreads();
    {
      const float4v* src4 = (const float4v*)Wsrc;
      float4v* W4 = (float4v*)W;
      for (int idx = t; idx < 1536; idx += 256) W4[idx] = src4[idx];
    }
    __syncthreads();
    float acc[4][4] = {{0.f}};
    #pragma unroll 4
    for (int k = 0; k < 48; k++){
      float4v xv = *(const float4v*)&xT[k][ng*4];
      float4v wv = *(const float4v*)&W[k][cg*4];
      #pragma unroll
      for (int i = 0; i < 4; i++)
        #pragma unroll
        for (int j = 0; j < 4; j++)
          acc[i][j] += xv[i]*wv[j];
    }
    #pragma unroll
    for (int i = 0; i < 4; i++){
      int n = n0 + ng*4 + i;
      if (n >= N_) continue;
      uint2 pv;
      pv.x = pack2(acc[i][0], acc[i][1]);
      pv.y = pack2(acc[i][2], acc[i][3]);
      if (seg == 0)      *(uint2*)&AC[(size_t)n*256 + cg*4] = pv;
      else if (seg == 1) *(uint2*)&Bn[(size_t)n*128 + cg*4] = pv;
      else               *(uint2*)&AC[(size_t)n*256 + 128 + cg*4] = pv;
    }
  }
}

// ---------------- edge BN stats pass (h1e = A[row]+B[col]) ----------------
__global__ __launch_bounds__(256) void k_estats(const int2* __restrict__ rcs,
    const uint16_t* __restrict__ AC, const uint16_t* __restrict__ Bn, float* __restrict__ estR){
  __shared__ float red[4][64][4];
  __shared__ float lst[256];
  int t = threadIdx.x, lane = t & 63, w = t >> 6;
  int wid = blockIdx.x * 4 + w, nw = gridDim.x * 4;
  float s0=0,q0=0,s1=0,q1=0;
  const uint32_t* ACu = (const uint32_t*)AC;
  const uint32_t* Bu  = (const uint32_t*)Bn;
  for (int e = wid; e < E_; e += nw){
    int2 rc = rcs[e];
    uint32_t pa = ACu[(size_t)rc.x*128 + lane];
    uint32_t pb = Bu[(size_t)rc.y*64 + lane];
    float a0,a1,b0,b1; unpack2(pa,a0,a1); unpack2(pb,b0,b1);
    float h0 = a0 + b0, h1 = a1 + b1;
    s0 += h0; q0 += h0*h0; s1 += h1; q1 += h1*h1;
  }
  red[w][lane][0]=s0; red[w][lane][1]=q0; red[w][lane][2]=s1; red[w][lane][3]=q1;
  __syncthreads();
  if (t < 64){
    float S0=0,Q0=0,S1=0,Q1=0;
    for (int ww = 0; ww < 4; ww++){ S0+=red[ww][t][0]; Q0+=red[ww][t][1]; S1+=red[ww][t][2]; Q1+=red[ww][t][3]; }
    lst[2*t] = S0; lst[2*t+1] = S1; lst[128+2*t] = Q0; lst[128+2*t+1] = Q1;
  }
  __syncthreads();
  atomicAdd(&estR[(blockIdx.x & 63)*256 + t], lst[t]);
}

// ---------------- generic BN finalize ----------------
__global__ void k_bnfin(const float* __restrict__ statsR, int reps, const float* __restrict__ g,
                        const float* __restrict__ be, float* __restrict__ s_out, float* __restrict__ t_out,
                        float inv_n){
  int c = threadIdx.x;
  if (c >= 128) return;
  float sm = 0.f, sq = 0.f;
  for (int r = 0; r < reps; r++){ sm += statsR[r*256 + c]; sq += statsR[r*256 + 128 + c]; }
  float m = sm * inv_n;
  float v = sq * inv_n - m*m;
  float s = g[c] / sqrtf(v + 1e-5f);
  s_out[c] = s;
  t_out[c] = be[c] - m*s;
}

// ======== edge MFMA passes v2: single gather window.
// rc read per-thread (no index LDS round-trip); C row prefetched into 16 VGPRs
// alongside A/B so all three gathers share one latency window; C lands in LDS
// via reg-write after the MFMA. Stride 132 + 8B LDS ops (R7-proven).

// ---------------- edge MFMA pass 0: n1 BN stats ----------------
__global__ __launch_bounds__(256) void k_epass0(
    const int2* __restrict__ rcs,
    const uint16_t* __restrict__ AC, const uint16_t* __restrict__ Bn,
    const uint16_t* __restrict__ Mt, const float* __restrict__ se, const float* __restrict__ te,
    float* __restrict__ n1R){
  __shared__ __align__(16) uint16_t bufA[64*132];   // relu tile -> C tile
  __shared__ __align__(16) uint16_t bufB[128*132];  // Mt -> acc tile (rows 0..63)
  __shared__ __align__(16) float sete[256];         // se | te
  __shared__ float lst[256];
  const int t = threadIdx.x;
  const long i0 = (long)blockIdx.x * 64;
  const int lane = t & 63, w = t >> 6;
  const int m = lane & 15, quad = lane >> 4;
  const int e = t >> 2, q = t & 3;

  // all three gathers issued up front, one latency window
  int2 rc = rcs[i0 + e];
  const uint4* Ap = (const uint4*)((const uint32_t*)AC + (size_t)rc.x*128 + q*16);
  const uint4* Bp = (const uint4*)((const uint32_t*)Bn + (size_t)rc.y*64  + q*16);
  const uint4* Cp = (const uint4*)((const uint32_t*)AC + (size_t)rc.x*128 + 64 + q*16);
  uint4 va0 = Ap[0], va1 = Ap[1], va2 = Ap[2], va3 = Ap[3];
  uint4 vb0 = Bp[0], vb1 = Bp[1], vb2 = Bp[2], vb3 = Bp[3];
  uint4 vc0 = Cp[0], vc1 = Cp[1], vc2 = Cp[2], vc3 = Cp[3];

  if (t < 128){ sete[t] = se[t]; sete[128 + t] = te[t]; }
  lst[t] = 0.f;
  __syncthreads();

  // P0: relu from regs -> bufA
  {
    uint32_t* dstd = (uint32_t*)bufA + e*66 + q*16;
    int cb = q*32;
    uint4 vas[4] = {va0, va1, va2, va3};
    uint4 vbs[4] = {vb0, vb1, vb2, vb3};
    #pragma unroll
    for (int u = 0; u < 4; u++){
      uint4 va = vas[u], vb = vbs[u];
      float4v sA = *(const float4v*)&sete[cb + u*8];
      float4v sB = *(const float4v*)&sete[cb + u*8 + 4];
      float4v tA = *(const float4v*)&sete[128 + cb + u*8];
      float4v tB = *(const float4v*)&sete[128 + cb + u*8 + 4];
      float a0,a1,b0,b1; uint4 o;
      unpack2(va.x,a0,a1); unpack2(vb.x,b0,b1);
      o.x = pack2(fmaxf(0.f,(a0+b0)*sA[0]+tA[0]), fmaxf(0.f,(a1+b1)*sA[1]+tA[1]));
      unpack2(va.y,a0,a1); unpack2(vb.y,b0,b1);
      o.y = pack2(fmaxf(0.f,(a0+b0)*sA[2]+tA[2]), fmaxf(0.f,(a1+b1)*sA[3]+tA[3]));
      unpack2(va.z,a0,a1); unpack2(vb.z,b0,b1);
      o.z = pack2(fmaxf(0.f,(a0+b0)*sB[0]+tB[0]), fmaxf(0.f,(a1+b1)*sB[1]+tB[1]));
      unpack2(va.w,a0,a1); unpack2(vb.w,b0,b1);
      o.w = pack2(fmaxf(0.f,(a0+b0)*sB[2]+tB[2]), fmaxf(0.f,(a1+b1)*sB[3]+tB[3]));
      lds_store16B_as8(dstd + u*4, o);
    }
  }
  // P1: stage Mt into bufB
  {
    int n = t >> 1, h = t & 1;
    const uint4* src = (const uint4*)((const uint32_t*)Mt + n*64 + h*32);
    uint32_t* dstd = (uint32_t*)bufB + n*66 + h*32;
    #pragma unroll
    for (int u = 0; u < 8; u++) lds_store16B_as8(dstd + u*4, src[u]);
  }
  __syncthreads();

  // P2: MFMA — 16 edges/wave x 128 cols, K=128
  float4v acc[8];
  #pragma unroll
  for (int nt = 0; nt < 8; nt++){ acc[nt][0]=0.f; acc[nt][1]=0.f; acc[nt][2]=0.f; acc[nt][3]=0.f; }
  {
    const uint16_t* aptr = bufA + (w*16 + m)*132 + quad*8;
    const uint16_t* bbase = bufB + m*132 + quad*8;
    #pragma unroll
    for (int ks = 0; ks < 4; ks++){
      short8 af = lds_load8(aptr + ks*32);
      #pragma unroll
      for (int nt = 0; nt < 8; nt++){
        short8 bf = lds_load8(bbase + nt*16*132 + ks*32);
        acc[nt] = __builtin_amdgcn_mfma_f32_16x16x32_bf16(af, bf, acc[nt], 0, 0, 0);
      }
    }
  }
  __syncthreads();

  // P3: C regs -> bufA; acc (bf16) -> bufB rows 0..63
  {
    uint32_t* dstd = (uint32_t*)bufA + e*66 + q*16;
    lds_store16B_as8(dstd + 0,  vc0);
    lds_store16B_as8(dstd + 4,  vc1);
    lds_store16B_as8(dstd + 8,  vc2);
    lds_store16B_as8(dstd + 12, vc3);
  }
  #pragma unroll
  for (int nt = 0; nt < 8; nt++)
    #pragma unroll
    for (int reg = 0; reg < 4; reg++)
      bufB[(w*16 + quad*4 + reg)*132 + nt*16 + m] = f2bf(acc[nt][reg]);
  __syncthreads();

  // P4: h = acc + C, batched stats
  {
    int cp = t & 63, eg = t >> 6;
    float ss0=0,qq0=0,ss1=0,qq1=0;
    #pragma unroll
    for (int it = 0; it < 16; it++){
      int ee = it*4 + eg;
      uint32_t ph = ((uint32_t*)bufB)[ee*66 + cp];
      uint32_t pc = ((uint32_t*)bufA)[ee*66 + cp];
      float h0,h1,c0,c1v;
      unpack2(ph,h0,h1); unpack2(pc,c0,c1v);
      float v0 = h0 + c0, v1 = h1 + c1v;
      ss0 += v0; qq0 += v0*v0; ss1 += v1; qq1 += v1*v1;
    }
    atomicAdd(&lst[2*cp], ss0);
    atomicAdd(&lst[2*cp+1], ss1);
    atomicAdd(&lst[128+2*cp], qq0);
    atomicAdd(&lst[128+2*cp+1], qq1);
  }
  __syncthreads();
  atomicAdd(&n1R[(blockIdx.x & 63)*256 + t], lst[t]);
}

// ---------------- edge MFMA pass 1: recompute, BN(n1)+relu, segment-aggregate ----------------
__global__ __launch_bounds__(256) void k_epass1(
    const int2* __restrict__ rcs,
    const uint16_t* __restrict__ AC, const uint16_t* __restrict__ Bn,
    const uint16_t* __restrict__ Mt, const float* __restrict__ se, const float* __restrict__ te,
    const float* __restrict__ sn1, const float* __restrict__ tn1,
    float* __restrict__ aggf){
  __shared__ __align__(16) uint16_t bufA[64*132];   // relu tile -> C tile
  __shared__ __align__(16) uint16_t bufB[128*132];  // Mt -> acc tile (rows 0..63) + segacc (rows 64+)
  __shared__ __align__(16) float sete[256];         // se|te -> sn1|tn1 after MFMA
  __shared__ int ssid_s[64], scseg_s[64];
  __shared__ int snseg;
  const int t = threadIdx.x;
  const long i0 = (long)blockIdx.x * 64;
  const int lane = t & 63, w = t >> 6;
  const int m = lane & 15, quad = lane >> 4;
  const int e = t >> 2, q = t & 3;

  uint32_t* bufBu = (uint32_t*)bufB;
  float* segacc = (float*)(bufBu + 4224);   // 24*128 floats, rows 64+ region

  // gathers up front
  int2 rc = rcs[i0 + e];
  const uint4* Ap = (const uint4*)((const uint32_t*)AC + (size_t)rc.x*128 + q*16);
  const uint4* Bp = (const uint4*)((const uint32_t*)Bn + (size_t)rc.y*64  + q*16);
  const uint4* Cp = (const uint4*)((const uint32_t*)AC + (size_t)rc.x*128 + 64 + q*16);
  uint4 va0 = Ap[0], va1 = Ap[1], va2 = Ap[2], va3 = Ap[3];
  uint4 vb0 = Bp[0], vb1 = Bp[1], vb2 = Bp[2], vb3 = Bp[3];
  uint4 vc0 = Cp[0], vc1 = Cp[1], vc2 = Cp[2], vc3 = Cp[3];

  if (t < 128){ sete[t] = se[t]; sete[128 + t] = te[t]; }
  // segment ids (first wave only; scol via its own rcs read)
  if (t < 64){
    int myc = rcs[i0 + t].y;
    int prevc = (t > 0) ? rcs[i0 + t - 1].y : myc;
    bool bnd = (t > 0) && (myc != prevc);
    unsigned long long mask = __ballot(bnd);
    int sid = __popcll(mask << (63 - t));
    ssid_s[t] = sid;
    if (bnd || t == 0) scseg_s[sid] = myc;
    if (t == 63) snseg = sid + 1;
  }
  __syncthreads();

  // P0: relu from regs -> bufA
  {
    uint32_t* dstd = (uint32_t*)bufA + e*66 + q*16;
    int cb = q*32;
    uint4 vas[4] = {va0, va1, va2, va3};
    uint4 vbs[4] = {vb0, vb1, vb2, vb3};
    #pragma unroll
    for (int u = 0; u < 4; u++){
      uint4 va = vas[u], vb = vbs[u];
      float4v sA = *(const float4v*)&sete[cb + u*8];
      float4v sB = *(const float4v*)&sete[cb + u*8 + 4];
      float4v tA = *(const float4v*)&sete[128 + cb + u*8];
      float4v tB = *(const float4v*)&sete[128 + cb + u*8 + 4];
      float a0,a1,b0,b1; uint4 o;
      unpack2(va.x,a0,a1); unpack2(vb.x,b0,b1);
      o.x = pack2(fmaxf(0.f,(a0+b0)*sA[0]+tA[0]), fmaxf(0.f,(a1+b1)*sA[1]+tA[1]));
      unpack2(va.y,a0,a1); unpack2(vb.y,b0,b1);
      o.y = pack2(fmaxf(0.f,(a0+b0)*sA[2]+tA[2]), fmaxf(0.f,(a1+b1)*sA[3]+tA[3]));
      unpack2(va.z,a0,a1); unpack2(vb.z,b0,b1);
      o.z = pack2(fmaxf(0.f,(a0+b0)*sB[0]+tB[0]), fmaxf(0.f,(a1+b1)*sB[1]+tB[1]));
      unpack2(va.w,a0,a1); unpack2(vb.w,b0,b1);
      o.w = pack2(fmaxf(0.f,(a0+b0)*sB[2]+tB[2]), fmaxf(0.f,(a1+b1)*sB[3]+tB[3]));
      lds_store16B_as8(dstd + u*4, o);
    }
  }
  // P1: stage Mt into bufB
  {
    int n = t >> 1, h = t & 1;
    const uint4* src = (const uint4*)((const uint32_t*)Mt + n*64 + h*32);
    uint32_t* dstd = bufBu + n*66 + h*32;
    #pragma unroll
    for (int u = 0; u < 8; u++) lds_store16B_as8(dstd + u*4, src[u]);
  }
  __syncthreads();

  // P2: MFMA
  float4v acc[8];
  #pragma unroll
  for (int nt = 0; nt < 8; nt++){ acc[nt][0]=0.f; acc[nt][1]=0.f; acc[nt][2]=0.f; acc[nt][3]=0.f; }
  {
    const uint16_t* aptr = bufA + (w*16 + m)*132 + quad*8;
    const uint16_t* bbase = bufB + m*132 + quad*8;
    #pragma unroll
    for (int ks = 0; ks < 4; ks++){
      short8 af = lds_load8(aptr + ks*32);
      #pragma unroll
      for (int nt = 0; nt < 8; nt++){
        short8 bf = lds_load8(bbase + nt*16*132 + ks*32);
        acc[nt] = __builtin_amdgcn_mfma_f32_16x16x32_bf16(af, bf, acc[nt], 0, 0, 0);
      }
    }
  }
  __syncthreads();

  // P3: C regs -> bufA; acc -> bufB rows 0..63; sete <- sn1|tn1; zero segacc
  {
    uint32_t* dstd = (uint32_t*)bufA + e*66 + q*16;
    lds_store16B_as8(dstd + 0,  vc0);
    lds_store16B_as8(dstd + 4,  vc1);
    lds_store16B_as8(dstd + 8,  vc2);
    lds_store16B_as8(dstd + 12, vc3);
  }
  #pragma unroll
  for (int nt = 0; nt < 8; nt++)
    #pragma unroll
    for (int reg = 0; reg < 4; reg++)
      bufB[(w*16 + quad*4 + reg)*132 + nt*16 + m] = f2bf(acc[nt][reg]);
  if (t < 128){ sete[t] = sn1[t]; sete[128 + t] = tn1[t]; }
  for (int i = t; i < 24*128; i += 256) segacc[i] = 0.f;
  __syncthreads();

  // P4: BN+relu on the fly, batched segment walk
  {
    int cp = t & 63, eg = t >> 6;
    float s0 = sete[2*cp], s1 = sete[2*cp+1];
    float b0 = sete[128+2*cp], b1 = sete[128+2*cp+1];
    int nseg = snseg;
    bool lp = (nseg <= 24);
    int cursid = ssid_s[eg*16];
    float r0 = 0.f, r1 = 0.f;
    for (int it = 0; it < 16; it++){
      int ee = eg*16 + it;
      uint32_t ph = bufBu[ee*66 + cp];
      uint32_t pc = ((uint32_t*)bufA)[ee*66 + cp];
      float h0,h1,c0,c1v;
      unpack2(ph,h0,h1); unpack2(pc,c0,c1v);
      float v0 = fmaxf(0.f, (h0+c0)*s0 + b0);
      float v1 = fmaxf(0.f, (h1+c1v)*s1 + b1);
      int sid = ssid_s[ee];
      if (sid != cursid){
        if (lp){ atomicAdd(&segacc[cursid*128 + 2*cp], r0); atomicAdd(&segacc[cursid*128 + 2*cp+1], r1); }
        else { int c = scseg_s[cursid];
               atomicAdd(&aggf[(size_t)c*128 + 2*cp], r0); atomicAdd(&aggf[(size_t)c*128 + 2*cp+1], r1); }
        cursid = sid; r0 = 0.f; r1 = 0.f;
      }
      r0 += v0; r1 += v1;
    }
    if (lp){ atomicAdd(&segacc[cursid*128 + 2*cp], r0); atomicAdd(&segacc[cursid*128 + 2*cp+1], r1); }
    else { int c = scseg_s[cursid];
           atomicAdd(&aggf[(size_t)c*128 + 2*cp], r0); atomicAdd(&aggf[(size_t)c*128 + 2*cp+1], r1); }
    __syncthreads();
    if (lp){
      for (int idx = t; idx < nseg*64; idx += 256){
        int s = idx >> 6, cpp = idx & 63;
        float v0 = segacc[s*128 + 2*cpp], v1 = segacc[s*128 + 2*cpp+1];
        int c = scseg_s[s];
        float* dst = &aggf[(size_t)c*128 + 2*cpp];
        if (s == 0 || s == nseg - 1){ atomicAdd(dst, v0); atomicAdd(dst+1, v1); }
        else { dst[0] = v0; dst[1] = v1; }   // middle col wholly owned by this block
      }
    }
  }
}

// ---------------- n2 GEMM ----------------
__global__ __launch_bounds__(256) void k_n2(const float* __restrict__ x,
    const float* __restrict__ sx, const float* __restrict__ tx,
    const float* __restrict__ aggf, const float* __restrict__ invc,
    const float* __restrict__ Wc, const float* __restrict__ c1, const int* __restrict__ counts,
    float* __restrict__ hn2, float* __restrict__ n2R){
  __shared__ float xT[44][36];
  __shared__ float wT[44][128];
  __shared__ float lst[256];
  int t = threadIdx.x;
  int n0 = blockIdx.x * 32;
  int cg = t & 31, ng = t >> 5;
  lst[t] = 0.f;
  float acc[4][4] = {{0.f}};
  for (int kc = 0; kc < 176; kc += 44){
    __syncthreads();
    for (int idx = t; idx < 32*44; idx += 256){
      int r = idx / 44, k = idx % 44;
      int n = n0 + r, kk = kc + k;
      float v = 0.f;
      if (n < N_){
        if (kk < 48) v = x[(size_t)n*48 + kk] * sx[kk] + tx[kk];
        else         v = aggf[(size_t)n*128 + (kk - 48)] * invc[n];
      }
      xT[k][r] = v;
    }
    for (int idx = t; idx < 44*128; idx += 256){
      int k = idx >> 7, c = idx & 127;
      wT[k][c] = Wc[(kc + k)*128 + c];
    }
    __syncthreads();
    for (int k = 0; k < 44; k++){
      float4v xv = *(const float4v*)&xT[k][ng*4];
      float4v wv = *(const float4v*)&wT[k][cg*4];
      #pragma unroll
      for (int i = 0; i < 4; i++)
        #pragma unroll
        for (int j = 0; j < 4; j++)
          acc[i][j] += xv[i]*wv[j];
    }
  }
  float csum[4] = {0,0,0,0}, cqs[4] = {0,0,0,0};
  for (int i = 0; i < 4; i++){
    int n = n0 + ng*4 + i;
    if (n >= N_) continue;
    bool ok = counts[n] > 0;
    float4v o;
    #pragma unroll
    for (int j = 0; j < 4; j++){
      float vv = acc[i][j] + (ok ? c1[cg*4 + j] : 0.f);
      o[j] = vv; csum[j] += vv; cqs[j] += vv*vv;
    }
    *(float4v*)&hn2[(size_t)n*128 + cg*4] = o;
  }
  #pragma unroll
  for (int j = 0; j < 4; j++){
    atomicAdd(&lst[cg*4 + j], csum[j]);
    atomicAdd(&lst[128 + cg*4 + j], cqs[j]);
  }
  __syncthreads();
  atomicAdd(&n2R[(blockIdx.x & 63)*256 + t], lst[t]);
}

// ---------------- graph offsets from sorted batch ----------------
__global__ void k_goff(const int* __restrict__ batch, int* __restrict__ goff){
  int g = threadIdx.x;
  int lo = 0, hi = N_;
  while (lo < hi){ int mid = (lo + hi) >> 1; if (batch[mid] < g) lo = mid + 1; else hi = mid; }
  goff[g] = lo;
  if (g == 0) goff[256] = N_;
}

// ---------------- per-graph mean of relu(bn(h_n2)) ----------------
__global__ __launch_bounds__(128) void k_gmean(const float* __restrict__ hn2, const int* __restrict__ goff,
    const float* __restrict__ sn2, const float* __restrict__ tn2, float* __restrict__ gmean){
  int g = blockIdx.x, c = threadIdx.x;
  int b = goff[g], e = goff[g+1];
  float s = sn2[c], tt = tn2[c], a = 0.f;
  for (int r = b; r < e; r++) a += fmaxf(0.f, hn2[(size_t)r*128 + c]*s + tt);
  gmean[g*128 + c] = (e > b) ? a/(float)(e - b) : 0.f;
}

// ---------------- hg = gmean@M3 + cond*c3, gl stats ----------------
__global__ __launch_bounds__(256) void k_hg(const float* __restrict__ gmean, const float* __restrict__ M3,
    const float* __restrict__ c3, const int* __restrict__ goff,
    float* __restrict__ hg, float* __restrict__ gls){
  int idx = blockIdx.x * 256 + threadIdx.x;
  int g = idx >> 7, c = idx & 127;
  float a = 0.f;
  for (int k = 0; k < 128; k++) a += gmean[g*128 + k] * M3[k*128 + c];
  if (goff[g+1] > goff[g]) a += c3[c];
  hg[idx] = a;
  atomicAdd(&gls[c], a);
  atomicAdd(&gls[128 + c], a*a);
}

// ---------------- final output ----------------
__global__ __launch_bounds__(256) void k_out(const float* __restrict__ hg, const float* __restrict__ sgl,
    const float* __restrict__ tgl, const float* __restrict__ glW2, const float* __restrict__ glb2,
    float* __restrict__ out){
  int idx = blockIdx.x * 256 + threadIdx.x;
  int g = idx >> 1, o = idx & 1;
  float a = 0.f;
  for (int c = 0; c < 128; c++){
    float r = fmaxf(0.f, hg[g*128 + c]*sgl[c] + tgl[c]);
    a += r * glW2[c*2 + o];
  }
  out[idx] = a + glb2[o];
}

extern "C" void kernel_launch(void* const* d_in, const int* in_sizes, int n_in,
                              void* d_out, int out_size, void* d_ws, size_t ws_size,
                              hipStream_t stream){
  const float* x     = (const float*)d_in[0];
  const int*   ei    = (const int*)d_in[1];
  const int*   batch = (const int*)d_in[2];
  const float* bn_g  = (const float*)d_in[3];
  const float* bn_b  = (const float*)d_in[4];
  const float* eW1   = (const float*)d_in[5];
  const float* e_g   = (const float*)d_in[7];
  const float* e_be  = (const float*)d_in[8];
  const float* eW2   = (const float*)d_in[9];
  const float* n1W1  = (const float*)d_in[11];
  const float* n1_g  = (const float*)d_in[13];
  const float* n1_be = (const float*)d_in[14];
  const float* n1W2  = (const float*)d_in[15];
  const float* n1b2  = (const float*)d_in[16];
  const float* n2W1  = (const float*)d_in[17];
  const float* n2_g  = (const float*)d_in[19];
  const float* n2_be = (const float*)d_in[20];
  const float* n2W2  = (const float*)d_in[21];
  const float* n2b2  = (const float*)d_in[22];
  const float* glW1  = (const float*)d_in[23];
  const float* gl_g  = (const float*)d_in[25];
  const float* gl_be = (const float*)d_in[26];
  const float* glW2  = (const float*)d_in[27];
  const float* glb2  = (const float*)d_in[28];
  float* out = (float*)d_out;

  char* w = (char*)d_ws;
  size_t off = 0;
  auto take = [&](size_t bytes) -> char* {
    char* p = w + off;
    off = (off + bytes + 511) & ~(size_t)511;
    return p;
  };

  const size_t ZONE_WORDS = 96 + 3*64*256 + 256 + N_;
  float* zone   = (float*)take(ZONE_WORDS * 4);
  float* xstats = zone;
  float* estR   = zone + 96;
  float* n1R    = zone + 96 + 64*256;
  float* n2R    = zone + 96 + 2*64*256;
  float* gls    = zone + 96 + 3*64*256;
  int*   counts = (int*)(zone + 96 + 3*64*256 + 256);

  float* sx = (float*)take(48*4);   float* tx = (float*)take(48*4);
  float* se = (float*)take(128*4);  float* te = (float*)take(128*4);
  float* sn1 = (float*)take(128*4); float* tn1 = (float*)take(128*4);
  float* sn2 = (float*)take(128*4); float* tn2 = (float*)take(128*4);
  float* sgl = (float*)take(128*4); float* tgl = (float*)take(128*4);
  float* c1 = (float*)take(128*4);  float* c3 = (float*)take(128*4);
  float* invc  = (float*)take((size_t)N_*4);
  float* Wcomb = (float*)take(176*128*4);
  float* M3    = (float*)take(128*128*4);
  float* gmean = (float*)take(G_*128*4);
  float* hg    = (float*)take(G_*128*4);
  int* offs = (int*)take((N_+1)*4);
  int* cur  = (int*)take(N_*4);
  int* goff = (int*)take(257*4);
  int* bsum = (int*)take(64*4);
  int* boff = (int*)take(64*4);
  uint16_t* Mt = (uint16_t*)take(128*128*2);
  uint16_t* AC = (uint16_t*)take((size_t)N_*256*2);
  uint16_t* Bn = (uint16_t*)take((size_t)N_*128*2);
  float* aggf  = (float*)take((size_t)N_*128*4);
  float* hn2   = (float*)take((size_t)N_*128*4);
  int2* rcs = (int2*)take((size_t)E_*8);

  if (off > ws_size) return;   // clean fail, no fault

  hipMemsetAsync(zone, 0, ZONE_WORDS*4, stream);
  hipMemsetAsync(aggf, 0, (size_t)N_*128*4, stream);

  const int NB = (N_ + 1023) / 1024;  // 49
  hipLaunchKernelGGL(k_xstats, dim3(252), dim3(256), 0, stream, x, xstats);
  hipLaunchKernelGGL(k_hist, dim3((E_+255)/256), dim3(256), 0, stream, ei, counts);
  hipLaunchKernelGGL(k_xfin, dim3(1), dim3(64), 0, stream, xstats, bn_g, bn_b, sx, tx);
  hipLaunchKernelGGL(k_scanA, dim3(NB), dim3(256), 0, stream, counts, bsum);
  hipLaunchKernelGGL(k_scanB, dim3(1), dim3(64), 0, stream, bsum, boff, offs, NB);
  hipLaunchKernelGGL(k_scanC, dim3(NB), dim3(256), 0, stream, counts, boff, offs, cur);
  hipLaunchKernelGGL(k_place, dim3((E_+255)/256), dim3(256), 0, stream, ei, cur, rcs);
  hipLaunchKernelGGL(k_invc, dim3((N_+255)/256), dim3(256), 0, stream, counts, invc);
  hipLaunchKernelGGL(k_wprep, dim3(217), dim3(256), 0, stream,
                     eW2, n1W1, n1W2, n2W1, n2W2, glW1, n1b2, n2b2, Mt, Wcomb, M3, c1, c3);
  hipLaunchKernelGGL(k_nodegemm, dim3((N_+31)/32), dim3(256), 0, stream,
                     x, sx, tx, eW1, n1W1, AC, Bn);
  hipLaunchKernelGGL(k_estats, dim3(1024), dim3(256), 0, stream, rcs, AC, Bn, estR);
  hipLaunchKernelGGL(k_bnfin, dim3(1), dim3(128), 0, stream, estR, 64, e_g, e_be, se, te, 1.f/(float)E_);
  hipLaunchKernelGGL(k_epass0, dim3(E_/64), dim3(256), 0, stream,
                     rcs, AC, Bn, Mt, se, te, n1R);
  hipLaunchKernelGGL(k_bnfin, dim3(1), dim3(128), 0, stream, n1R, 64, n1_g, n1_be, sn1, tn1, 1.f/(float)E_);
  hipLaunchKernelGGL(k_epass1, dim3(E_/64), dim3(256), 0, stream,
                     rcs, AC, Bn, Mt, se, te, sn1, tn1, aggf);
  hipLaunchKernelGGL(k_n2, dim3((N_+31)/32), dim3(256), 0, stream,
                     x, sx, tx, aggf, invc, Wcomb, c1, counts, hn2, n2R);
  hipLaunchKernelGGL(k_bnfin, dim3(1), dim3(128), 0, stream, n2R, 64, n2_g, n2_be, sn2, tn2, 1.f/(float)N_);
  hipLaunchKernelGGL(k_goff, dim3(1), dim3(256), 0, stream, batch, goff);
  hipLaunchKernelGGL(k_gmean, dim3(256), dim3(128), 0, stream, hn2, goff, sn2, tn2, gmean);
  hipLaunchKernelGGL(k_hg, dim3(128), dim3(256), 0, stream, gmean, M3, c3, goff, hg, gls);
  hipLaunchKernelGGL(k_bnfin, dim3(1), dim3(128), 0, stream, gls, 1, gl_g, gl_be, sgl, tgl, 1.f/(float)G_);
  hipLaunchKernelGGL(k_out, dim3(2), dim3(256), 0, stream, hg, sgl, tgl, glW2, glb2, out);
}